// Round 24
// baseline (1202.099 us; speedup 1.0000x reference)
//
#include <hip/hip_runtime.h>
#include <math.h>

// ---------------- problem constants ----------------
#define BATCH 2
#define TSEQ 1024
#define DIMD 1024
#define NPERS 16
#define NCH 8
#define NTOK 2064
#define ETA_C 0.9f
#define THETA_C 0.1f
#define ALPHA_C 0.02f

typedef __attribute__((ext_vector_type(4))) float f32x4;
typedef __attribute__((ext_vector_type(8))) short s16x8;
typedef unsigned short u16;

// ---------------- bf16 helpers ----------------
__device__ __forceinline__ u16 f2bf(float f) {
    unsigned int u = __float_as_uint(f);
    return (u16)((u + 0x7fffu + ((u >> 16) & 1u)) >> 16);
}
__device__ __forceinline__ float bf2f(u16 h) { return __uint_as_float(((unsigned)h) << 16); }
__device__ __forceinline__ void split2(float v, u16& h, u16& l) {
    h = f2bf(v); l = f2bf(v - bf2f(h));
}

// ---------------- workspace layout (byte offsets) ----------------
static const size_t oRA = 0;                       // 50,724,864 multiplexed
static const size_t oRB = 50724864;                // 16,908,288
static const size_t oRC = 67633152;                // 12,582,912
static const size_t oRD = 80216064;                // 16,777,216
static const size_t oRE = 96993280;                // 12,582,912 Wqkv h/l (persistent)
static const size_t oRF = 109576192;               //  4,194,304 parW h/l (persistent)
static const size_t oRG = 113770496;               //  4,200,448 par (persistent)
static const size_t oRH = 117970944;               //  8,388,608 outb f32 / fQ split
// total 126,359,552 bytes

static const size_t PW1 = 0, PB1 = 524288, PW2 = 524800, PB2 = 1049088, PSZ = 1050112;

// ---------------- async global->LDS ----------------
__device__ __forceinline__ void gload_lds16(const u16* g, u16* l) {
    __builtin_amdgcn_global_load_lds(
        (const __attribute__((address_space(1))) unsigned int*)g,
        (__attribute__((address_space(3))) unsigned int*)l, 16, 0, 0);
}

// XCD-chunked block swizzle (bijective when nwg % 8 == 0; identity fallback).
__device__ __forceinline__ void xcd_swz2(int cmaj, int& bx, int& by) {
    int gx = gridDim.x, gy = gridDim.y, nwg = gx * gy;
    int lid = cmaj ? (blockIdx.x * gy + blockIdx.y) : (blockIdx.y * gx + blockIdx.x);
    int t = lid;
    if ((nwg & 7) == 0) {
        int q = nwg >> 3;
        t = (lid & 7) * q + (lid >> 3);
    }
    if (cmaj) { by = t % gy; bx = t / gy; }
    else      { bx = t % gx; by = t / gx; }
}
__device__ __forceinline__ void xcd_swizzle(int& bx, int& by) { xcd_swz2(0, bx, by); }

// stage one 128x32 bf16 tile into tile base `buf` (this wave's slot)
__device__ __forceinline__ void stage_tile(const u16* sp, u16* buf, int rbase,
                                           int M, int clampM, int K, int k0,
                                           int lane) {
    const int lr = lane >> 2, lc = lane & 3;
    #pragma unroll
    for (int i = 0; i < 8; ++i) {
        int r = i * 16 + lr;
        int gr = rbase + r;
        if (clampM && gr >= M) gr = M - 1;
        int g = lc ^ ((r >> 1) & 3);
        gload_lds16(sp + (size_t)gr * K + k0 + g * 8, buf + i * 512);
    }
}

// stage one 128x64 bf16 tile into tile base `buf` (scan path, BK=64)
__device__ __forceinline__ void stage_tile64(const u16* sp, u16* buf, int rbase,
                                             int K, int k0, int lane) {
    const int lr = lane >> 3, lc = lane & 7;
    #pragma unroll
    for (int i = 0; i < 16; ++i) {
        int r = i * 8 + lr;
        int gr = rbase + r;
        int g = lc ^ (r & 7);
        gload_lds16(sp + (size_t)gr * K + k0 + g * 8, buf + i * 512);
    }
}

// shared BK=32 dbuf main loop: accumulates into acc[4][4].
// NPROD=3: hh+hl+lh (fp32-quality), 4 LDS tiles/buffer.
// NPROD=2: hh+hl (drops al term, ~2^-9 rel err), 3 LDS tiles/buffer.
template<int NPROD>
__device__ __forceinline__ void mm_loop32(u16* lds,
                const u16* sp, int rbase, int M, int clampM, int K,
                int kbeg, int kend, int wid, int lane, int wm, int wn,
                f32x4 acc[4][4]) {
    constexpr int TILES = (NPROD == 3) ? 4 : 3;
    constexpr int BUF = TILES * 4096;
    constexpr int WOFF = (NPROD == 3) ? 2 : 1;     // W-hi tile slot
    const int frow = lane & 15, kblk = lane >> 4;
    const int nt = (kend - kbeg) >> 5;
    const int doStage = (NPROD == 3) || (wid != 1);   // skip unused A-low staging
    const int stile = (NPROD == 3) ? wid : ((wid == 0) ? 0 : wid - 1);
    if (doStage) stage_tile(sp, lds + stile * 4096, rbase, M, clampM, K, kbeg, lane);
    for (int t = 0; t < nt; ++t) {
        __syncthreads();
        if (t + 1 < nt && doStage)
            stage_tile(sp, lds + ((t + 1) & 1) * BUF + stile * 4096, rbase, M, clampM, K,
                       kbeg + ((t + 1) << 5), lane);
        const u16* cb = lds + (t & 1) * BUF;
        s16x8 bh[4], bl[4];
        #pragma unroll
        for (int ni = 0; ni < 4; ++ni) {
            int br = wn * 64 + ni * 16 + frow;
            int pc = kblk ^ ((br >> 1) & 3);
            bh[ni] = *(const s16x8*)&cb[WOFF * 4096 + br * 32 + pc * 8];
            bl[ni] = *(const s16x8*)&cb[(WOFF + 1) * 4096 + br * 32 + pc * 8];
        }
        #pragma unroll
        for (int mi = 0; mi < 4; ++mi) {
            int ar = wm * 64 + mi * 16 + frow;
            int pc = kblk ^ ((ar >> 1) & 3);
            s16x8 ah = *(const s16x8*)&cb[0 * 4096 + ar * 32 + pc * 8];
            s16x8 al;
            if (NPROD == 3) al = *(const s16x8*)&cb[1 * 4096 + ar * 32 + pc * 8];
            #pragma unroll
            for (int ni = 0; ni < 4; ++ni) {
                acc[mi][ni] = __builtin_amdgcn_mfma_f32_16x16x32_bf16(ah, bh[ni], acc[mi][ni], 0, 0, 0);
                acc[mi][ni] = __builtin_amdgcn_mfma_f32_16x16x32_bf16(ah, bl[ni], acc[mi][ni], 0, 0, 0);
                if (NPROD == 3)
                    acc[mi][ni] = __builtin_amdgcn_mfma_f32_16x16x32_bf16(al, bh[ni], acc[mi][ni], 0, 0, 0);
            }
        }
    }
}

// ---------------- split-bf16 MFMA GEMM:  C = act(A @ W^T + bias) ----------------
template<int ACTF, int WF32, int WSPLIT, int PARTIAL, int NPROD>
__global__ __launch_bounds__(256)
void gemm_mfma_k(const u16* __restrict__ Ah, const u16* __restrict__ Al,
                 const u16* __restrict__ Wh, const u16* __restrict__ Wl,
                 float* __restrict__ C, u16* __restrict__ Chi, u16* __restrict__ Clo,
                 int M, int N, int K, const float* __restrict__ bias, int cmaj)
{
    constexpr int TILES = (NPROD == 3) ? 4 : 3;
    __shared__ u16 lds[2 * TILES * 4096];
    const int tid = threadIdx.x;
    const int lane = tid & 63, wid = tid >> 6;
    const int wm = wid >> 1, wn = wid & 1;
    int bx, by; xcd_swz2(cmaj, bx, by);
    const int row0 = by * 128, col0 = bx * 128;
    const u16* sp = (wid == 0) ? Ah : (wid == 1) ? Al : (wid == 2) ? Wh : Wl;
    const int rbase = (wid < 2) ? row0 : col0;
    const int clampM = (wid < 2) ? 1 : 0;
    f32x4 acc[4][4] = {};
    int kbeg = 0, kend = K;
    if (PARTIAL) {
        int Kseg = K / gridDim.z;
        kbeg = blockIdx.z * Kseg;
        kend = kbeg + Kseg;
    }
    mm_loop32<NPROD>(&lds[0], sp, rbase, M, clampM, K, kbeg, kend, wid, lane, wm, wn, acc);

    const int erow = (lane >> 4) * 4, ecol = lane & 15;
    #pragma unroll
    for (int mi = 0; mi < 4; ++mi) {
        #pragma unroll
        for (int ni = 0; ni < 4; ++ni) {
            int c = col0 + wn * 64 + ni * 16 + ecol;
            float bv = (!PARTIAL && bias) ? bias[c] : 0.f;
            #pragma unroll
            for (int reg = 0; reg < 4; ++reg) {
                int r = row0 + wm * 64 + mi * 16 + erow + reg;
                if (r >= M) continue;
                float v = acc[mi][ni][reg] + bv;
                if (PARTIAL) {
                    C[((size_t)blockIdx.z * M + r) * N + c] = v;
                    continue;
                }
                if (ACTF == 1) v = v / (1.f + __expf(-v));
                else if (ACTF == 2) {
                    float u = 0.7978845608028654f * (v + 0.044715f * v * v * v);
                    v = 0.5f * v * (1.f + tanhf(u));
                }
                size_t o = (size_t)r * N + c;
                if (WF32) C[o] = v;
                if (WSPLIT) { u16 h, l; split2(v, h, l); Chi[o] = h; Clo[o] = l; }
            }
        }
    }
}

// fused qkv GEMM (2-product, 3-tile LDS): Q hi, kc hi, kcT split, V f32
__global__ __launch_bounds__(256)
void gemm_qkv_k(const u16* __restrict__ Ah, const u16* __restrict__ Al,
                const u16* __restrict__ Wh, const u16* __restrict__ Wl,
                u16* __restrict__ Qh, u16* __restrict__ Ql,
                u16* __restrict__ kch, u16* __restrict__ kcl,
                u16* __restrict__ kcTh, u16* __restrict__ kcTl,
                float* __restrict__ Vb, int M, int N, int K)
{
    __shared__ u16 lds[2 * 3 * 4096];
    const int tid = threadIdx.x;
    const int lane = tid & 63, wid = tid >> 6;
    const int wm = wid >> 1, wn = wid & 1;
    int bx, by; xcd_swz2(1, bx, by);
    const int row0 = by * 128, col0 = bx * 128;
    const u16* sp = (wid == 0) ? Ah : (wid == 1) ? Al : (wid == 2) ? Wh : Wl;
    const int rbase = (wid < 2) ? row0 : col0;
    f32x4 acc[4][4] = {};
    mm_loop32<2>(&lds[0], sp, rbase, M, 0, K, 0, K, wid, lane, wm, wn, acc);

    const int erow = (lane >> 4) * 4, ecol = lane & 15;
    #pragma unroll
    for (int mi = 0; mi < 4; ++mi) {
        #pragma unroll
        for (int ni = 0; ni < 4; ++ni) {
            int c = col0 + wn * 64 + ni * 16 + ecol;
            #pragma unroll
            for (int reg = 0; reg < 4; ++reg) {
                int r = row0 + wm * 64 + mi * 16 + erow + reg;
                float v = acc[mi][ni][reg];
                int b = r >> 10, t = r & 1023;
                if (c < 1024) {
                    size_t o = (size_t)r * 1024 + c;
                    Qh[o] = f2bf(v);
                } else if (c < 2048) {
                    int d = c - 1024;
                    int ch = t >> 7, rr = t & 127;
                    size_t o = ((size_t)((ch * 2 + b) * 128 + rr)) * 1024 + d;
                    u16 h, l; split2(v, h, l);
                    kch[o] = h;
                    size_t ot = (size_t)ch * 262144 + (size_t)d * 256 + b * 128 + rr;
                    kcTh[ot] = h; kcTl[ot] = l;
                } else {
                    int d = c - 2048;
                    int ch = t >> 7, rr = t & 127;
                    Vb[((size_t)((ch * 2 + b) * 128 + rr)) * 1024 + d] = v;
                }
            }
        }
    }
}

// fused attention-qkv GEMM (2-product, 3-tile LDS): fQ hi (0.125-scaled),
// fK split, fV^T hi
__global__ __launch_bounds__(256)
void gemm_aqkv_k(const u16* __restrict__ Ah, const u16* __restrict__ Al,
                 const u16* __restrict__ Wh, const u16* __restrict__ Wl,
                 u16* __restrict__ fQh, u16* __restrict__ fQl,
                 u16* __restrict__ fKh, u16* __restrict__ fKl,
                 u16* __restrict__ fVt, int M, int N, int K)
{
    __shared__ u16 lds[2 * 3 * 4096];
    const int tid = threadIdx.x;
    const int lane = tid & 63, wid = tid >> 6;
    const int wm = wid >> 1, wn = wid & 1;
    int bx, by; xcd_swz2(1, bx, by);
    // dead Q tiles: cols<1024 only used for query rows n>=1040
    if (bx < 8 && ((by <= 7) || (by >= 17 && by <= 23))) return;
    const int row0 = by * 128, col0 = bx * 128;
    const u16* sp = (wid == 0) ? Ah : (wid == 1) ? Al : (wid == 2) ? Wh : Wl;
    const int rbase = (wid < 2) ? row0 : col0;
    const int clampM = (wid < 2) ? 1 : 0;
    f32x4 acc[4][4] = {};
    mm_loop32<2>(&lds[0], sp, rbase, M, clampM, K, 0, K, wid, lane, wm, wn, acc);

    const int erow = (lane >> 4) * 4, ecol = lane & 15;
    #pragma unroll
    for (int mi = 0; mi < 4; ++mi) {
        #pragma unroll
        for (int ni = 0; ni < 4; ++ni) {
            int c = col0 + wn * 64 + ni * 16 + ecol;
            #pragma unroll
            for (int reg = 0; reg < 4; ++reg) {
                int r = row0 + wm * 64 + mi * 16 + erow + reg;
                if (r >= M) continue;
                float v = acc[mi][ni][reg];
                int b = (r >= 2064) ? 1 : 0;
                int n = r - b * 2064;
                if (c < 1024) {
                    if (n >= NPERS + TSEQ) {
                        int h = c >> 6, d = c & 63;
                        int row = n - (NPERS + TSEQ);
                        size_t o = (((size_t)(b * 16 + h)) * 1024 + row) * 64 + d;
                        fQh[o] = f2bf(0.125f * v);
                    }
                } else if (c < 2048) {
                    int cc = c - 1024;
                    int h = cc >> 6, d = cc & 63;
                    size_t o = (((size_t)(b * 16 + h)) * NTOK + n) * 64 + d;
                    u16 hh, ll; split2(v, hh, ll);
                    fKh[o] = hh; fKl[o] = ll;
                } else {
                    int cc = c - 2048;
                    int h = cc >> 6, d = cc & 63;
                    fVt[(((size_t)(b * 16 + h)) * 64 + d) * NTOK + n] = f2bf(v);
                }
            }
        }
    }
}

// split-K reduce + epilogue
template<int ACTF, int WF32, int WSPLIT>
__global__ __launch_bounds__(256)
void reduce_k(const float* __restrict__ Cp, int S,
              float* __restrict__ C, u16* __restrict__ Chi, u16* __restrict__ Clo,
              const float* __restrict__ bias, int M, int N)
{
    int i = blockIdx.x * 256 + threadIdx.x;
    int n4 = (int)((size_t)M * N / 4);
    if (i >= n4) return;
    size_t off = (size_t)i * 4;
    float4 v = *(const float4*)&Cp[off];
    for (int z = 1; z < S; ++z) {
        float4 u = *(const float4*)&Cp[(size_t)z * M * N + off];
        v.x += u.x; v.y += u.y; v.z += u.z; v.w += u.w;
    }
    int c = (int)(off % N);
    float vv[4] = {v.x, v.y, v.z, v.w};
    #pragma unroll
    for (int j = 0; j < 4; ++j) {
        float w = vv[j];
        if (bias) w += bias[c + j];
        if (ACTF == 1) w = w / (1.f + __expf(-w));
        else if (ACTF == 2) {
            float u = 0.7978845608028654f * (w + 0.044715f * w * w * w);
            w = 0.5f * w * (1.f + tanhf(u));
        }
        if (WF32) C[off + j] = w;
        if (WSPLIT) { u16 h, l; split2(w, h, l); Chi[off + j] = h; Clo[off + j] = l; }
    }
}

// memtok reduce: sum S=2 partials + b2, write split DIRECTLY into token rows
__global__ __launch_bounds__(256)
void reduce_tok_k(const float* __restrict__ Cp, const float* __restrict__ bias,
                  u16* __restrict__ th, u16* __restrict__ tl)
{
    int i = blockIdx.x * 256 + threadIdx.x;
    if (i >= 524288) return;
    size_t off = (size_t)i * 4;
    float4 v = *(const float4*)&Cp[off];
    float4 u = *(const float4*)&Cp[2097152 + off];
    v.x += u.x; v.y += u.y; v.z += u.z; v.w += u.w;
    int r = (int)(off >> 10), c = (int)(off & 1023);
    int b = r >> 10, t = r & 1023;
    size_t orow = (((size_t)(b * NTOK + NPERS + t)) << 10) + c;
    float vv[4] = {v.x + bias[c], v.y + bias[c + 1], v.z + bias[c + 2], v.w + bias[c + 3]};
    u16 h0,l0,h1,l1,h2,l2,h3,l3;
    split2(vv[0],h0,l0); split2(vv[1],h1,l1); split2(vv[2],h2,l2); split2(vv[3],h3,l3);
    ushort4 hv = {h0,h1,h2,h3}, lv = {l0,l1,l2,l3};
    *(ushort4*)&th[orow] = hv;
    *(ushort4*)&tl[orow] = lv;
}

static void gemm_mfma(hipStream_t s, int act, int wf32, int wsplit,
                      const u16* Ah, const u16* Al, const u16* Wh, const u16* Wl,
                      float* C, u16* Ch, u16* Cl, int M, int N, int K,
                      const float* bias, int nprod = 3, int cmaj = 0)
{
    dim3 g(N / 128, (M + 127) / 128), b(256);
    if (act == 0 && wf32 == 1 && wsplit == 0)
        gemm_mfma_k<0,1,0,0,3><<<g,b,0,s>>>(Ah,Al,Wh,Wl,C,Ch,Cl,M,N,K,bias,cmaj);
    else if (act == 0 && wf32 == 1 && wsplit == 1)
        gemm_mfma_k<0,1,1,0,3><<<g,b,0,s>>>(Ah,Al,Wh,Wl,C,Ch,Cl,M,N,K,bias,cmaj);
    else if (act == 0 && wf32 == 0 && wsplit == 1)
        gemm_mfma_k<0,0,1,0,3><<<g,b,0,s>>>(Ah,Al,Wh,Wl,C,Ch,Cl,M,N,K,bias,cmaj);
    else if (act == 1)
        gemm_mfma_k<1,0,1,0,3><<<g,b,0,s>>>(Ah,Al,Wh,Wl,C,Ch,Cl,M,N,K,bias,cmaj);
    else if (nprod == 2)
        gemm_mfma_k<2,0,1,0,2><<<g,b,0,s>>>(Ah,Al,Wh,Wl,C,Ch,Cl,M,N,K,bias,cmaj);
    else
        gemm_mfma_k<2,0,1,0,3><<<g,b,0,s>>>(Ah,Al,Wh,Wl,C,Ch,Cl,M,N,K,bias,cmaj);
}

static void gemm_mfma_sk(hipStream_t s, int act, int wf32, int wsplit,
                         const u16* Ah, const u16* Al, const u16* Wh, const u16* Wl,
                         float* C, u16* Ch, u16* Cl, int M, int N, int K,
                         const float* bias, int S, float* part, int nprod = 3,
                         int cmaj = 0)
{
    if (S <= 1) { gemm_mfma(s, act, wf32, wsplit, Ah, Al, Wh, Wl, C, Ch, Cl, M, N, K, bias, nprod, cmaj); return; }
    dim3 g(N / 128, (M + 127) / 128, S), b(256);
    if (nprod == 2)
        gemm_mfma_k<0,0,0,1,2><<<g,b,0,s>>>(Ah,Al,Wh,Wl,part,nullptr,nullptr,M,N,K,nullptr,cmaj);
    else
        gemm_mfma_k<0,0,0,1,3><<<g,b,0,s>>>(Ah,Al,Wh,Wl,part,nullptr,nullptr,M,N,K,nullptr,cmaj);
    int n4 = (int)((size_t)M * N / 4);
    dim3 rg((n4 + 255) / 256), rb(256);
    if (act == 0 && wf32 == 1 && wsplit == 0)
        reduce_k<0,1,0><<<rg,rb,0,s>>>(part, S, C, Ch, Cl, bias, M, N);
    else if (act == 0 && wf32 == 1 && wsplit == 1)
        reduce_k<0,1,1><<<rg,rb,0,s>>>(part, S, C, Ch, Cl, bias, M, N);
    else if (act == 0 && wf32 == 0 && wsplit == 1)
        reduce_k<0,0,1><<<rg,rb,0,s>>>(part, S, C, Ch, Cl, bias, M, N);
    else if (act == 1)
        reduce_k<1,0,1><<<rg,rb,0,s>>>(part, S, C, Ch, Cl, bias, M, N);
    else
        reduce_k<2,0,1><<<rg,rb,0,s>>>(part, S, C, Ch, Cl, bias, M, N);
}

// ---------------- scan-specialized split-bf16 MFMA GEMM body (BK=64 dbuf) -------
// NPROD=2: drops A-low product; 3 tiles/buffer, 96 KB LDS.
// MODE 6: gW1 GEMM with FUSED momentum update (bit-identical to grd round-trip).
template<int MODE, int NPROD>
__device__ __forceinline__ void scan_body(u16* lds, int bx, int by,
                 const u16* __restrict__ Ah, const u16* __restrict__ Al,
                 const u16* __restrict__ Wh, const u16* __restrict__ Wl,
                 float* __restrict__ C, u16* __restrict__ Chi, u16* __restrict__ Clo,
                 u16* __restrict__ ChiT, u16* __restrict__ CloT,
                 const float* __restrict__ Zf, const float* __restrict__ add,
                 const float* __restrict__ bias, float* __restrict__ CP,
                 float* __restrict__ MO,
                 int M, int N, int K, float alpha)
{
    constexpr int TILES = (NPROD == 3) ? 4 : 3;
    constexpr int BUF = TILES * 8192;
    constexpr int WOFF = (NPROD == 3) ? 2 : 1;
    const int tid = threadIdx.x;
    const int lane = tid & 63, wid = tid >> 6;
    const int wm = wid >> 1, wn = wid & 1;
    const int row0 = by * 128, col0 = bx * 128;

    const u16* sp = (wid == 0) ? Ah : (wid == 1) ? Al : (wid == 2) ? Wh : Wl;
    const int rbase = (wid < 2) ? row0 : col0;
    const int doStage = (NPROD == 3) || (wid != 1);
    const int stile = (NPROD == 3) ? wid : ((wid == 0) ? 0 : wid - 1);

    f32x4 acc[4][4] = {};
    const int frow = lane & 15, kblk = lane >> 4;
    const int nt = K >> 6;

    if (doStage) stage_tile64(sp, lds + stile * 8192, rbase, K, 0, lane);

    for (int t = 0; t < nt; ++t) {
        __syncthreads();
        if (t + 1 < nt && doStage)
            stage_tile64(sp, lds + ((t + 1) & 1) * BUF + stile * 8192, rbase, K,
                         (t + 1) << 6, lane);
        const u16* cb = lds + (t & 1) * BUF;

        #pragma unroll
        for (int s = 0; s < 2; ++s) {
            s16x8 bh[4], bl[4];
            #pragma unroll
            for (int ni = 0; ni < 4; ++ni) {
                int br = wn * 64 + ni * 16 + frow;
                int pc = (s * 4 + kblk) ^ (br & 7);
                bh[ni] = *(const s16x8*)&cb[WOFF * 8192 + br * 64 + pc * 8];
                bl[ni] = *(const s16x8*)&cb[(WOFF + 1) * 8192 + br * 64 + pc * 8];
            }
            #pragma unroll
            for (int mi = 0; mi < 4; ++mi) {
                int ar = wm * 64 + mi * 16 + frow;
                int pc = (s * 4 + kblk) ^ (ar & 7);
                s16x8 ah = *(const s16x8*)&cb[0 * 8192 + ar * 64 + pc * 8];
                s16x8 al;
                if (NPROD == 3) al = *(const s16x8*)&cb[1 * 8192 + ar * 64 + pc * 8];
                #pragma unroll
                for (int ni = 0; ni < 4; ++ni) {
                    acc[mi][ni] = __builtin_amdgcn_mfma_f32_16x16x32_bf16(ah, bh[ni], acc[mi][ni], 0, 0, 0);
                    acc[mi][ni] = __builtin_amdgcn_mfma_f32_16x16x32_bf16(ah, bl[ni], acc[mi][ni], 0, 0, 0);
                    if (NPROD == 3)
                        acc[mi][ni] = __builtin_amdgcn_mfma_f32_16x16x32_bf16(al, bh[ni], acc[mi][ni], 0, 0, 0);
                }
            }
        }
    }

    const int erow = (lane >> 4) * 4, ecol = lane & 15;
    float csum[4] = {0.f, 0.f, 0.f, 0.f};
    #pragma unroll
    for (int mi = 0; mi < 4; ++mi) {
        #pragma unroll
        for (int ni = 0; ni < 4; ++ni) {
            int c = col0 + wn * 64 + ni * 16 + ecol;
            #pragma unroll
            for (int reg = 0; reg < 4; ++reg) {
                int r = row0 + wm * 64 + mi * 16 + erow + reg;
                float v = acc[mi][ni][reg];
                size_t o = (size_t)r * N + c;
                if (MODE == 1) {
                    v += bias[c];
                    C[o] = v;
                    float hv = v / (1.f + __expf(-v));
                    u16 h, l; split2(hv, h, l);
                    Chi[o] = h; Clo[o] = l;
                    size_t ot = (size_t)c * M + r;
                    ChiT[ot] = h; CloT[ot] = l;
                } else if (MODE == 2) {
                    v += bias[c] - add[o];
                    u16 h, l; split2(v, h, l);
                    Chi[o] = h; Clo[o] = l;
                    size_t ot = (size_t)c * M + r;
                    ChiT[ot] = h; CloT[ot] = l;
                    csum[ni] += v;
                } else if (MODE == 3) {
                    C[o] = alpha * v;
                } else if (MODE == 6) {
                    // fused W1 momentum update (gi = v, alpha = 1)
                    float m = ETA_C * MO[o] - THETA_C * v;
                    MO[o] = m;
                    float pv = (1.f - ALPHA_C) * C[o] + m;
                    C[o] = pv;
                    u16 h, l; split2(pv, h, l);
                    Chi[o] = h; Clo[o] = l;
                } else {
                    v *= alpha;
                    float z = Zf[o];
                    float sg = 1.f / (1.f + __expf(-z));
                    v *= sg * (1.f + z * (1.f - sg));
                    u16 h, l; split2(v, h, l);
                    size_t ot = (size_t)c * M + r;
                    ChiT[ot] = h; CloT[ot] = l;
                    csum[ni] += v;
                }
            }
        }
    }
    if (MODE == 2 || MODE == 4) {
        #pragma unroll
        for (int ni = 0; ni < 4; ++ni) {
            float s = csum[ni];
            s += __shfl_xor(s, 16);
            s += __shfl_xor(s, 32);
            if ((lane >> 4) == 0) {
                int c = col0 + wn * 64 + ni * 16 + ecol;
                float w = (MODE == 2) ? alpha * s : s;
                CP[(size_t)(by * 2 + wm) * N + c] = w;
            }
        }
    }
}

template<int MODE>
__global__ __launch_bounds__(256)
void gemm_scan_k(const u16* __restrict__ Ah, const u16* __restrict__ Al,
                 const u16* __restrict__ Wh, const u16* __restrict__ Wl,
                 float* __restrict__ C, u16* __restrict__ Chi, u16* __restrict__ Clo,
                 u16* __restrict__ ChiT, u16* __restrict__ CloT,
                 const float* __restrict__ Zf, const float* __restrict__ add,
                 const float* __restrict__ bias, float* __restrict__ CP,
                 int M, int N, int K, float alpha)
{
    __shared__ u16 lds[2 * 3 * 8192];       // 96 KB (2-product)
    int bx, by; xcd_swizzle(bx, by);
    scan_body<MODE, 2>(&lds[0], bx, by, Ah, Al, Wh, Wl, C, Chi, Clo, ChiT, CloT,
                       Zf, add, bias, CP, nullptr, M, N, K, alpha);
}

// merged launch: gW2 (MODE3, 4x8 tiles at by<8) || dh (MODE4, 4x2 tiles at by>=8)
__global__ __launch_bounds__(256)
void gemm_scan_pair_k(const u16* __restrict__ rTh, const u16* __restrict__ rTl,
                      const u16* __restrict__ hTh, const u16* __restrict__ hTl,
                      float* __restrict__ gW2,
                      const u16* __restrict__ rh_, const u16* __restrict__ rl_,
                      const u16* __restrict__ w2th, const u16* __restrict__ w2tl,
                      u16* __restrict__ dhTh, u16* __restrict__ dhTl,
                      const float* __restrict__ z1, float* __restrict__ cp1, float cs)
{
    __shared__ u16 lds[2 * 3 * 8192];       // 96 KB (2-product)
    if (blockIdx.y < 8) {
        scan_body<3, 2>(&lds[0], blockIdx.x, blockIdx.y, rTh, rTl, hTh, hTl,
                        gW2, nullptr, nullptr, nullptr, nullptr, nullptr, nullptr,
                        nullptr, nullptr, nullptr, 1024, 512, 256, cs);
    } else {
        scan_body<4, 2>(&lds[0], blockIdx.x, blockIdx.y - 8, rh_, rl_, w2th, w2tl,
                        nullptr, nullptr, nullptr, dhTh, dhTl, z1, nullptr,
                        nullptr, cp1, nullptr, 256, 512, 1024, cs);
    }
}

// merged: gW1 GEMM + fused W1 update (by<4) || W2 update from grd (by>=4) || biases
__global__ __launch_bounds__(256)
void gemm_gw1up_k(const u16* __restrict__ dhTh, const u16* __restrict__ dhTl,
                  const u16* __restrict__ kth, const u16* __restrict__ ktl,
                  float* __restrict__ par, float* __restrict__ mo,
                  u16* __restrict__ w1h, u16* __restrict__ w1l,
                  u16* __restrict__ w2h, u16* __restrict__ w2l,
                  u16* __restrict__ w2th, u16* __restrict__ w2tl,
                  const float* __restrict__ g2,
                  const float* __restrict__ cp1, const float* __restrict__ cp2)
{
    __shared__ u16 lds[2 * 3 * 8192];
    const int tid = threadIdx.x;
    if (blockIdx.y < 4) {
        // gW1 = dhT @ kcT^T with fused momentum update (M=512, N=1024, K=256)
        scan_body<6, 2>(&lds[0], blockIdx.x, blockIdx.y, dhTh, dhTl, kth, ktl,
                        par, w1h, w1l, nullptr, nullptr, nullptr, nullptr,
                        nullptr, nullptr, mo, 512, 1024, 256, 1.f);
    } else {
        // W2 momentum update from grd+PW2 (written by prior pair launch)
        int uid = (blockIdx.y - 4) * 8 + blockIdx.x;   // 0..63
        #pragma unroll
        for (int it = 0; it < 32; ++it) {
            int j = uid * 8192 + it * 256 + tid;       // < 524288
            float gi = g2[j];
            size_t i = 524800 + (size_t)j;
            float m = ETA_C * mo[i] - THETA_C * gi;
            mo[i] = m;
            float pv = (1.f - ALPHA_C) * par[i] + m;
            par[i] = pv;
            u16 h, l; split2(pv, h, l);
            w2h[j] = h; w2l[j] = l;
            int tj = (j & 511) * 1024 + (j >> 9);
            w2th[tj] = h; w2tl[tj] = l;
        }
        if (uid == 0) {
            for (int jj = tid; jj < 1536; jj += 256) {
                size_t i; float gi;
                if (jj < 512) {
                    i = 524288 + jj;
                    gi = cp1[jj] + cp1[512 + jj] + cp1[1024 + jj] + cp1[1536 + jj];
                } else {
                    int j2 = jj - 512;
                    i = 1049088 + j2;
                    gi = cp2[j2] + cp2[1024 + j2] + cp2[2048 + j2] + cp2[3072 + j2];
                }
                float m = ETA_C * mo[i] - THETA_C * gi;
                mo[i] = m;
                par[i] = (1.f - ALPHA_C) * par[i] + m;
            }
        }
    }
}

// ---------------- small kernels ----------------
__global__ void cvt_split_k(const float* __restrict__ in, u16* __restrict__ hi,
                            u16* __restrict__ lo, int n4) {
    int i = blockIdx.x * 256 + threadIdx.x;
    if (i >= n4) return;
    float4 v = *(const float4*)&in[(size_t)i * 4];
    u16 h0,l0,h1,l1,h2,l2,h3,l3;
    split2(v.x,h0,l0); split2(v.y,h1,l1); split2(v.z,h2,l2); split2(v.w,h3,l3);
    ushort4 hv = {h0,h1,h2,h3}, lv = {l0,l1,l2,l3};
    *(ushort4*)&hi[(size_t)i * 4] = hv;
    *(ushort4*)&lo[(size_t)i * 4] = lv;
}
__global__ void transpose_split_k(const float* __restrict__ in, u16* __restrict__ outh,
                                  u16* __restrict__ outl, int R, int C) {
    __shared__ float t[32][33];
    const int c0 = blockIdx.x * 32, r0 = blockIdx.y * 32;
    const size_t zoff = (size_t)blockIdx.z * R * C;
    const int tx = threadIdx.x & 31, ty = threadIdx.x >> 5;
    #pragma unroll
    for (int p = 0; p < 4; ++p) {
        int r = ty + p * 8;
        t[r][tx] = in[zoff + (size_t)(r0 + r) * C + c0 + tx];
    }
    __syncthreads();
    #pragma unroll
    for (int p = 0; p < 4; ++p) {
        int cc = ty + p * 8;
        float v = t[tx][cc];
        u16 h, l; split2(v, h, l);
        size_t o = zoff + (size_t)(c0 + cc) * R + r0 + tx;
        outh[o] = h; outl[o] = l;
    }
}
// fill ONLY persist (P) and x rows of the token split buffers
__global__ void tokens_px_k(const float* __restrict__ P, const float* __restrict__ x,
                            u16* __restrict__ th, u16* __restrict__ tl) {
    size_t idx = (size_t)blockIdx.x * 256 + threadIdx.x;   // 2*1040*1024
    if (idx >= (size_t)2 * 1040 * 1024) return;
    int d = (int)(idx & 1023);
    int rl = (int)((idx >> 10) % 1040);
    int b = (int)(idx / ((size_t)1040 * 1024));
    float v; int n;
    if (rl < NPERS) { v = P[(size_t)rl * 1024 + d]; n = rl; }
    else { int t = rl - NPERS; v = x[((size_t)b * TSEQ + t) * 1024 + d]; n = NPERS + TSEQ + t; }
    size_t o = (((size_t)(b * NTOK + n)) << 10) + d;
    u16 h, l; split2(v, h, l); th[o] = h; tl[o] = l;
}
__global__ void mul_k(const float* __restrict__ a, const float* __restrict__ b,
                      float* __restrict__ o, int n) {
    int i = blockIdx.x * 256 + threadIdx.x;
    if (i < n) o[i] = a[i] * b[i];
}

// ---------------- MFMA flash attention: split-KV partial + merge ----------------
// Fixed-shift softmax (m == 0). P hi-only; Q hi-only (2-product QK^T, K split kept).
// Row-sum l via ones-column MFMA.
__global__ __launch_bounds__(256)
void flash_part_k(const u16* __restrict__ Qsh,
                  const u16* __restrict__ Ksh, const u16* __restrict__ Ksl,
                  const u16* __restrict__ Vts, float* __restrict__ Of,
                  float* __restrict__ Lf)
{
    __shared__ u16 lds[16384];             // KH KL VT | PH = 32 KB
    u16* KH = lds;            u16* KL = lds + 4096;
    u16* VT = lds + 8192;
    u16* PH = lds + 12288;

    int lid = blockIdx.x + (blockIdx.y << 4) + (blockIdx.z << 8);
    int t1024 = ((lid & 7) << 7) | (lid >> 3);
    const int qt = t1024 & 15, h = (t1024 >> 4) & 15;
    const int zb = t1024 >> 8;
    const int b = zb >> 1, z = zb & 1;

    const int tid = threadIdx.x;
    const int lane = tid & 63, wid = tid >> 6;
    const int fr = lane & 15, kq = lane >> 4;
    const int bh = b * 16 + h;
    const int q0c = qt * 64;
    const int q0a = NPERS + TSEQ + q0c;
    const int ntile = ((q0a + 63) >> 6) + 1;
    const int half = ntile >> 1;
    const int jt0 = z ? half : 0;
    const int jt1 = z ? ntile : half;
    const int l8 = lane & 7, lr8 = lane >> 3;

    auto stageKV = [&](int jt) {
        const int j0 = jt * 64;
        #pragma unroll
        for (int jj = 0; jj < 6; ++jj) {
            int j = wid * 6 + jj;
            int buf = j >> 3, i8 = j & 7;
            if (buf < 2) {
                int row = i8 * 8 + lr8;
                int grow = j0 + row; if (grow > NTOK - 1) grow = NTOK - 1;
                int c = l8 ^ (row & 7);
                const u16* src = (buf == 0 ? Ksh : Ksl) +
                                 (((size_t)bh * NTOK + grow) << 6) + c * 8;
                gload_lds16(src, (buf == 0 ? KH : KL) + i8 * 512);
            } else {
                int d = i8 * 8 + lr8;
                int c = l8 ^ (d & 7);
                int col = j0 + c * 8; if (col > NTOK - 8) col = NTOK - 8;
                const u16* src = Vts + ((size_t)bh * 64 + d) * NTOK + col;
                gload_lds16(src, VT + i8 * 512);
            }
        }
    };

    // Q fragments direct from global (hi only)
    s16x8 qh[2];
    {
        const size_t qrow = ((size_t)bh * 1024 + q0c + wid * 16 + fr) << 6;
        #pragma unroll
        for (int kb = 0; kb < 2; ++kb)
            qh[kb] = *(const s16x8*)&Qsh[qrow + (size_t)(kb * 4 + kq) * 8];
    }

    // ones fragment (bf16 1.0) for the l row-sum MFMA
    s16x8 ones;
    #pragma unroll
    for (int i = 0; i < 8; ++i) ones[i] = (short)0x3F80;

    f32x4 Oa[4] = {};
    f32x4 lacc = {};

    for (int jt = jt0; jt < jt1; ++jt) {
        const int j0 = jt * 64;
        stageKV(jt);
        __syncthreads();                    // KV landed

        f32x4 sacc[4] = {};
        __builtin_amdgcn_s_setprio(1);
        #pragma unroll
        for (int nt = 0; nt < 4; ++nt) {
            #pragma unroll
            for (int kb = 0; kb < 2; ++kb) {
                int br = nt * 16 + fr;
                int sl = (kb * 4 + kq) ^ (fr & 7);
                s16x8 kh = *(const s16x8*)&KH[br * 64 + sl * 8];
                s16x8 kl = *(const s16x8*)&KL[br * 64 + sl * 8];
                sacc[nt] = __builtin_amdgcn_mfma_f32_16x16x32_bf16(qh[kb], kh, sacc[nt], 0, 0, 0);
                sacc[nt] = __builtin_amdgcn_mfma_f32_16x16x32_bf16(qh[kb], kl, sacc[nt], 0, 0, 0);
            }
        }
        __builtin_amdgcn_s_setprio(0);

        // fixed-shift softmax: p = exp(s) masked, store bf16-hi only
        #pragma unroll
        for (int r = 0; r < 4; ++r) {
            const int qloc = kq * 4 + r;
            const int qi = q0a + wid * 16 + qloc;
            const int prow = wid * 16 + qloc;
            #pragma unroll
            for (int nt = 0; nt < 4; ++nt) {
                int kj = j0 + nt * 16 + fr;
                float e = (kj <= qi) ? __expf(sacc[nt][r]) : 0.f;
                int col = nt * 16 + fr;
                int sl = (col >> 3) ^ (qloc & 7);
                PH[prow * 64 + sl * 8 + (col & 7)] = f2bf(e);
            }
        }

        // PV + l row-sum (ones column) on the matrix pipe
        __builtin_amdgcn_s_setprio(1);
        #pragma unroll
        for (int kb = 0; kb < 2; ++kb) {
            int pr = wid * 16 + fr;
            int sl = (kb * 4 + kq) ^ (fr & 7);
            s16x8 pa = *(const s16x8*)&PH[pr * 64 + sl * 8];
            lacc = __builtin_amdgcn_mfma_f32_16x16x32_bf16(pa, ones, lacc, 0, 0, 0);
            #pragma unroll
            for (int dt = 0; dt < 4; ++dt) {
                int vr = dt * 16 + fr;
                s16x8 vb = *(const s16x8*)&VT[vr * 64 + sl * 8];
                Oa[dt] = __builtin_amdgcn_mfma_f32_16x16x32_bf16(pa, vb, Oa[dt], 0, 0, 0);
            }
        }
        __builtin_amdgcn_s_setprio(0);
        __syncthreads();                    // compute done before next stage overwrites
    }

    const size_t obase = ((((size_t)z * 2 + b) * 16 + h) * 16 + qt) * 4096;
    const size_t mlb   = ((((size_t)z * 2 + b) * 16 + h) * 16 + qt) * 64;
    #pragma unroll
    for (int r = 0; r < 4; ++r) {
        int rl = wid * 16 + kq * 4 + r;
        if (fr == 0) Lf[mlb + rl] = lacc[r];
        #pragma unroll
        for (int dt = 0; dt < 4; ++dt)
            Of[obase + (size_t)rl * 64 + dt * 16 + fr] = Oa[dt][r];
    }
}

// merge: O = (O0 + O1) / (l0 + l1)
__global__ __launch_bounds__(256)
void flash_merge_k(const float* __restrict__ Of, const float* __restrict__ Lf,
                   u16* __restrict__ oh, u16* __restrict__ ol)
{
    const int qt = blockIdx.x, h = blockIdx.y, b = blockIdx.z;
    const int tid = threadIdx.x;
    const int row = tid >> 2, quad = tid & 3;
    const size_t b0 = ((((size_t)0 * 2 + b) * 16 + h) * 16 + qt) * 4096 + (size_t)row * 64;
    const size_t b1 = ((((size_t)1 * 2 + b) * 16 + h) * 16 + qt) * 4096 + (size_t)row * 64;
    const size_t m0i = ((((size_t)0 * 2 + b) * 16 + h) * 16 + qt) * 64 + row;
    const size_t m1i = ((((size_t)1 * 2 + b) * 16 + h) * 16 + qt) * 64 + row;
    float inv = 1.f / (Lf[m0i] + Lf[m1i]);
    const size_t orow = ((size_t)(b * 1024 + qt * 64 + row)) * 1024 + h * 64;
    #pragma unroll
    for (int i = 0; i < 4; ++i) {
        int col = quad * 16 + i * 4;
        float4 v0 = *(const float4*)&Of[b0 + col];
        float4 v1 = *(const float4*)&Of[b1 + col];
        float o0 = (v0.x + v1.x) * inv;
        float o1 = (v0.y + v1.y) * inv;
        float o2 = (v0.z + v1.z) * inv;
        float o3 = (v0.w + v1.w) * inv;
        u16 h0,l0_,h1,l1_,h2,l2_,h3,l3_;
        split2(o0,h0,l0_); split2(o1,h1,l1_); split2(o2,h2,l2_); split2(o3,h3,l3_);
        ushort4 hv = {h0,h1,h2,h3}, lv = {l0_,l1_,l2_,l3_};
        *(ushort4*)&oh[orow + col] = hv;
        *(ushort4*)&ol[orow + col] = lv;
    }
}

// ---------------- launch ----------------
extern "C" void kernel_launch(void* const* d_in, const int* in_sizes, int n_in,
                              void* d_out, int out_size, void* d_ws, size_t ws_size,
                              hipStream_t stream)
{
    const float* x     = (const float*)d_in[0];
    const float* Wqkv  = (const float*)d_in[1];
    const float* mW1   = (const float*)d_in[2];
    const float* mb1   = (const float*)d_in[3];
    const float* mW2   = (const float*)d_in[4];
    const float* mb2   = (const float*)d_in[5];
    const float* Pp    = (const float*)d_in[6];
    const float* Wqa   = (const float*)d_in[7];
    const float* Wo    = (const float*)d_in[8];
    const float* ffW1  = (const float*)d_in[9];
    const float* ffb1  = (const float*)d_in[10];
    const float* ffW2  = (const float*)d_in[11];
    const float* ffb2  = (const float*)d_in[12];
    char* wsb = (char*)d_ws;
    float* outp = (float*)d_out;

    // region A (multiplexed)
    float* z1    = (float*)(wsb + oRA);
    float* grd   = (float*)(wsb + oRA + 3145728);
    float* cp2   = (float*)(wsb + oRA + 7346176);
    float* cp1   = (float*)(wsb + oRA + 7362560);
    u16* hh_     = (u16*)(wsb + oRA + 8388608);
    u16* hl_     = (u16*)(wsb + oRA + 8650752);
    u16* hTh     = (u16*)(wsb + oRA + 9437184);
    u16* hTl     = (u16*)(wsb + oRA + 9699328);
    u16* rh_     = (u16*)(wsb + oRA + 10485760);
    u16* rl_     = (u16*)(wsb + oRA + 11010048);
    u16* rTh     = (u16*)(wsb + oRA + 11534336);
    u16* rTl     = (u16*)(wsb + oRA + 12058624);
    u16* dhTh    = (u16*)(wsb + oRA + 12582912);
    u16* dhTl    = (u16*)(wsb + oRA + 12845056);
    u16* kcTh    = (u16*)(wsb + oRA + 16777216);
    u16* kcTl    = (u16*)(wsb + oRA + 20971520);
    // flash partials + attn operands (region A dead between scan and FFN)
    float* Of    = (float*)(wsb + oRA);                   // 16.78 MB
    float* Lf    = (float*)(wsb + oRA + 16777216);        // 0.26 MB
    u16* fVth    = (u16*)(wsb + oRA + 17825792);          // 8.45 MB
    u16* fKl     = (u16*)(wsb + oRA + 26279936);          // 8.45 MB
    u16* Woh     = (u16*)(wsb + oRA);
    u16* Wol     = (u16*)(wsb + oRA + 2097152);
    u16* ffhh    = (u16*)(wsb + oRA);
    u16* ffhl    = (u16*)(wsb + oRA + 16777216);
    u16* outbh   = (u16*)(wsb + oRA + 33554432);
    u16* outbl   = (u16*)(wsb + oRA + 37748736);
    u16* newQh   = (u16*)(wsb + oRA);
    u16* newQl   = (u16*)(wsb + oRA + 4194304);
    u16* hzh     = (u16*)(wsb + oRA + 8388608);
    u16* hzl     = (u16*)(wsb + oRA + 10485760);
    float* memq  = (float*)(wsb + oRA + 12582912);
    float* partA0 = (float*)(wsb + oRA);
    float* partA1 = (float*)(wsb + oRA + 4194304);
    float* partA2 = (float*)(wsb + oRA + 16777216);
    // region B
    float* Vb    = (float*)(wsb + oRB + 8388608);
    u16* tokh    = (u16*)(wsb + oRB);
    u16* tokl    = (u16*)(wsb + oRB + 8454144);
    u16* oh      = (u16*)(wsb + oRB);
    u16* ol      = (u16*)(wsb + oRB + 4194304);
    u16* y1h     = (u16*)(wsb + oRB + 8388608);
    u16* y1l     = (u16*)(wsb + oRB + 12582912);
    float* partB = (float*)(wsb + oRB);
    // region C
    u16* xh      = (u16*)(wsb + oRC);
    u16* xl      = (u16*)(wsb + oRC + 4194304);
    float* mom   = (float*)(wsb + oRC);
    u16* pW2Th   = (u16*)(wsb + oRC + 5242880);
    u16* pW2Tl   = (u16*)(wsb + oRC + 6291456);
    u16* Wqah    = (u16*)(wsb + oRC);
    u16* Wqal    = (u16*)(wsb + oRC + 6291456);
    // region D
    u16* Qh      = (u16*)(wsb + oRD);
    u16* Ql      = (u16*)(wsb + oRD + 4194304);
    u16* kchh    = (u16*)(wsb + oRD + 8388608);
    u16* kchl    = (u16*)(wsb + oRD + 12582912);
    u16* t1h     = (u16*)(wsb + oRD + 8388608);
    u16* t1l     = (u16*)(wsb + oRD + 10485760);
    u16* fKh     = (u16*)(wsb + oRD);
    u16* ffW1h   = (u16*)(wsb + oRD);
    u16* ffW1l   = (u16*)(wsb + oRD + 8388608);
    u16* ffW2h   = (u16*)(wsb + oRD);
    u16* ffW2l   = (u16*)(wsb + oRD + 8388608);
    // persistent
    u16* Wqkvh   = (u16*)(wsb + oRE);
    u16* Wqkvl   = (u16*)(wsb + oRE + 6291456);
    u16* pW1h    = (u16*)(wsb + oRF);
    u16* pW1l    = (u16*)(wsb + oRF + 1048576);
    u16* pW2h    = (u16*)(wsb + oRF + 2097152);
    u16* pW2l    = (u16*)(wsb + oRF + 3145728);
    float* par   = (float*)(wsb + oRG);
    float* outb  = (float*)(wsb + oRH);
    u16* fQh     = (u16*)(wsb + oRH);
    u16* fQl     = (u16*)(wsb + oRH + 4194304);

    // init memory-MLP params
    hipMemcpyAsync(par + PW1, mW1, 524288 * sizeof(float), hipMemcpyDeviceToDevice, stream);
    hipMemcpyAsync(par + PB1, mb1, 512 * sizeof(float), hipMemcpyDeviceToDevice, stream);
    hipMemcpyAsync(par + PW2, mW2, 524288 * sizeof(float), hipMemcpyDeviceToDevice, stream);
    hipMemcpyAsync(par + PB2, mb2, 1024 * sizeof(float), hipMemcpyDeviceToDevice, stream);

    // qkv = x @ Wqkv^T (fused epilogue; 2-product; column-major XCD chunks)
    cvt_split_k<<<2048, 256, 0, stream>>>(x, xh, xl, 524288);
    cvt_split_k<<<3072, 256, 0, stream>>>(Wqkv, Wqkvh, Wqkvl, 786432);
    gemm_qkv_k<<<dim3(24, 16), 256, 0, stream>>>(xh, xl, Wqkvh, Wqkvl,
        Qh, Ql, kchh, kchl, kcTh, kcTl, Vb, 2048, 3072, 1024);

    // scan prep (xh/xl dead now)
    hipMemsetAsync(mom, 0, PSZ * sizeof(float), stream);
    cvt_split_k<<<512, 256, 0, stream>>>(par + PW1, pW1h, pW1l, 131072);
    cvt_split_k<<<512, 256, 0, stream>>>(par + PW2, pW2h, pW2l, 131072);
    transpose_split_k<<<dim3(16, 32, 1), 256, 0, stream>>>(par + PW2, pW2Th, pW2Tl, 1024, 512);

    // memory scan: z1 -> r -> {gW2 || dh} -> {gW1+W1up || W2up || biases}
    const float cs = 2.f / (float)(BATCH * 128 * DIMD);
    for (int c = 0; c < NCH; ++c) {
        const u16* kch = kchh + (size_t)c * 262144;
        const u16* kcl = kchl + (size_t)c * 262144;
        const u16* kth = kcTh + (size_t)c * 262144;
        const u16* ktl = kcTl + (size_t)c * 262144;
        const float* vc = Vb + (size_t)c * 262144;
        gemm_scan_k<1><<<dim3(4, 2), 256, 0, stream>>>(kch, kcl, pW1h, pW1l,
            z1, hh_, hl_, hTh, hTl, nullptr, nullptr, par + PB1, nullptr, 256, 512, 1024, 1.f);
        gemm_scan_k<2><<<dim3(8, 2), 256, 0, stream>>>(hh_, hl_, pW2h, pW2l,
            nullptr, rh_, rl_, rTh, rTl, nullptr, vc, par + PB2, cp2, 256, 1024, 512, cs);
        gemm_scan_pair_k<<<dim3(4, 10), 256, 0, stream>>>(rTh, rTl, hTh, hTl, grd + PW2,
            rh_, rl_, pW2Th, pW2Tl, dhTh, dhTl, z1, cp1, cs);
        gemm_gw1up_k<<<dim3(8, 12), 256, 0, stream>>>(dhTh, dhTl, kth, ktl,
            par, mom, pW1h, pW1l, pW2h, pW2l, pW2Th, pW2Tl, grd + PW2, cp1, cp2);
    }

    // memory readout: t1 (split-K S=4, 2-prod), memtok partial (2-prod) -> tok rows
    gemm_mfma_sk(stream, 1, 0, 1, Qh, Ql, pW1h, pW1l, nullptr, t1h, t1l,
                 2048, 512, 1024, par + PB1, 4, partA2, 2);
    {
        dim3 g(8, 16, 2), b(256);
        gemm_mfma_k<0,0,0,1,2><<<g, b, 0, stream>>>(t1h, t1l, pW2h, pW2l,
            partA0, nullptr, nullptr, 2048, 1024, 512, nullptr, 0);
        reduce_tok_k<<<2048, 256, 0, stream>>>(partA0, par + PB2, tokh, tokl);
    }

    // P + x token rows, weights, fused attention qkv (2-product, dead-Q-tile skip)
    tokens_px_k<<<8320, 256, 0, stream>>>(Pp, x, tokh, tokl);
    cvt_split_k<<<3072, 256, 0, stream>>>(Wqa, Wqah, Wqal, 786432);
    gemm_aqkv_k<<<dim3(24, 33), 256, 0, stream>>>(tokh, tokl, Wqah, Wqal,
        fQh, fQl, fKh, fKl, fVth, 4128, 3072, 1024);

    // MFMA flash attention: fixed-shift softmax, P/Q hi-only, MFMA row-sum
    flash_part_k<<<dim3(16, 16, 4), 256, 0, stream>>>(fQh, fKh, fKl, fVth, Of, Lf);
    flash_merge_k<<<dim3(16, 16, 2), 256, 0, stream>>>(Of, Lf, oh, ol);

    // Wo projection + FFN (split-K; 2-product; FF1 column-major chunks)
    cvt_split_k<<<1024, 256, 0, stream>>>(Wo, Woh, Wol, 262144);
    gemm_mfma_sk(stream, 0, 0, 1, oh, ol, Woh, Wol, nullptr, y1h, y1l,
                 2048, 1024, 1024, nullptr, 2, partA1, 2);
    cvt_split_k<<<4096, 256, 0, stream>>>(ffW1, ffW1h, ffW1l, 1048576);
    gemm_mfma(stream, 2, 0, 1, y1h, y1l, ffW1h, ffW1l, nullptr, ffhh, ffhl,
              2048, 4096, 1024, ffb1, 2, 1);
    cvt_split_k<<<4096, 256, 0, stream>>>(ffW2, ffW2h, ffW2l, 1048576);
    gemm_mfma_sk(stream, 0, 1, 1, ffhh, ffhl, ffW2h, ffW2l, outb, outbh, outbl,
                 2048, 1024, 4096, ffb2, 2, partB, 2);

    // gate (newQ/hz 2-product; memq 3-product endpoint anchor)
    gemm_mfma_sk(stream, 0, 0, 1, outbh, outbl, Wqkvh, Wqkvl, nullptr, newQh, newQl,
                 2048, 1024, 1024, nullptr, 2, partB, 2);
    gemm_mfma_sk(stream, 1, 0, 1, newQh, newQl, pW1h, pW1l, nullptr, hzh, hzl,
                 2048, 512, 1024, par + PB1, 4, partB, 2);
    gemm_mfma_sk(stream, 0, 1, 0, hzh, hzl, pW2h, pW2l, memq, nullptr, nullptr,
                 2048, 1024, 512, par + PB2, 2, partB, 3);
    mul_k<<<8192, 256, 0, stream>>>(outb, memq, outp, 2097152);
}

// Round 25
// 1146.908 us; speedup vs baseline: 1.0481x; 1.0481x over previous
//
#include <hip/hip_runtime.h>
#include <math.h>

// ---------------- problem constants ----------------
#define BATCH 2
#define TSEQ 1024
#define DIMD 1024
#define NPERS 16
#define NCH 8
#define NTOK 2064
#define ETA_C 0.9f
#define THETA_C 0.1f
#define ALPHA_C 0.02f

typedef __attribute__((ext_vector_type(4))) float f32x4;
typedef __attribute__((ext_vector_type(8))) short s16x8;
typedef unsigned short u16;

// ---------------- bf16 helpers ----------------
__device__ __forceinline__ u16 f2bf(float f) {
    unsigned int u = __float_as_uint(f);
    return (u16)((u + 0x7fffu + ((u >> 16) & 1u)) >> 16);
}
__device__ __forceinline__ float bf2f(u16 h) { return __uint_as_float(((unsigned)h) << 16); }
__device__ __forceinline__ void split2(float v, u16& h, u16& l) {
    h = f2bf(v); l = f2bf(v - bf2f(h));
}

// ---------------- workspace layout (byte offsets) ----------------
static const size_t oRA = 0;                       // 50,724,864 multiplexed
static const size_t oRB = 50724864;                // 16,908,288
static const size_t oRC = 67633152;                // 12,582,912
static const size_t oRD = 80216064;                // 16,777,216
static const size_t oRE = 96993280;                // 12,582,912 Wqkv h/l (persistent)
static const size_t oRF = 109576192;               //  4,194,304 parW h/l (persistent)
static const size_t oRG = 113770496;               //  4,200,448 par (persistent)
static const size_t oRH = 117970944;               //  8,388,608 outb f32 / fQ split
// total 126,359,552 bytes

static const size_t PW1 = 0, PB1 = 524288, PW2 = 524800, PB2 = 1049088, PSZ = 1050112;

// ---------------- async global->LDS ----------------
__device__ __forceinline__ void gload_lds16(const u16* g, u16* l) {
    __builtin_amdgcn_global_load_lds(
        (const __attribute__((address_space(1))) unsigned int*)g,
        (__attribute__((address_space(3))) unsigned int*)l, 16, 0, 0);
}

// XCD-chunked block swizzle (bijective when nwg % 8 == 0; identity fallback).
__device__ __forceinline__ void xcd_swz2(int cmaj, int& bx, int& by) {
    int gx = gridDim.x, gy = gridDim.y, nwg = gx * gy;
    int lid = cmaj ? (blockIdx.x * gy + blockIdx.y) : (blockIdx.y * gx + blockIdx.x);
    int t = lid;
    if ((nwg & 7) == 0) {
        int q = nwg >> 3;
        t = (lid & 7) * q + (lid >> 3);
    }
    if (cmaj) { by = t % gy; bx = t / gy; }
    else      { bx = t % gx; by = t / gx; }
}
__device__ __forceinline__ void xcd_swizzle(int& bx, int& by) { xcd_swz2(0, bx, by); }

// stage one 128x32 bf16 tile into tile base `buf` (this wave's slot)
__device__ __forceinline__ void stage_tile(const u16* sp, u16* buf, int rbase,
                                           int M, int clampM, int K, int k0,
                                           int lane) {
    const int lr = lane >> 2, lc = lane & 3;
    #pragma unroll
    for (int i = 0; i < 8; ++i) {
        int r = i * 16 + lr;
        int gr = rbase + r;
        if (clampM && gr >= M) gr = M - 1;
        int g = lc ^ ((r >> 1) & 3);
        gload_lds16(sp + (size_t)gr * K + k0 + g * 8, buf + i * 512);
    }
}

// stage one 128x64 bf16 tile into tile base `buf` (scan path, BK=64)
__device__ __forceinline__ void stage_tile64(const u16* sp, u16* buf, int rbase,
                                             int K, int k0, int lane) {
    const int lr = lane >> 3, lc = lane & 7;
    #pragma unroll
    for (int i = 0; i < 16; ++i) {
        int r = i * 8 + lr;
        int gr = rbase + r;
        int g = lc ^ (r & 7);
        gload_lds16(sp + (size_t)gr * K + k0 + g * 8, buf + i * 512);
    }
}

// shared BK=32 dbuf main loop: accumulates into acc[4][4].
// NPROD=3: hh+hl+lh (fp32-quality), 4 LDS tiles/buffer.
// NPROD=2: hh+hl (drops al term, ~2^-9 rel err), 3 LDS tiles/buffer.
template<int NPROD>
__device__ __forceinline__ void mm_loop32(u16* lds,
                const u16* sp, int rbase, int M, int clampM, int K,
                int kbeg, int kend, int wid, int lane, int wm, int wn,
                f32x4 acc[4][4]) {
    constexpr int TILES = (NPROD == 3) ? 4 : 3;
    constexpr int BUF = TILES * 4096;
    constexpr int WOFF = (NPROD == 3) ? 2 : 1;     // W-hi tile slot
    const int frow = lane & 15, kblk = lane >> 4;
    const int nt = (kend - kbeg) >> 5;
    const int doStage = (NPROD == 3) || (wid != 1);   // skip unused A-low staging
    const int stile = (NPROD == 3) ? wid : ((wid == 0) ? 0 : wid - 1);
    if (doStage) stage_tile(sp, lds + stile * 4096, rbase, M, clampM, K, kbeg, lane);
    for (int t = 0; t < nt; ++t) {
        __syncthreads();
        if (t + 1 < nt && doStage)
            stage_tile(sp, lds + ((t + 1) & 1) * BUF + stile * 4096, rbase, M, clampM, K,
                       kbeg + ((t + 1) << 5), lane);
        const u16* cb = lds + (t & 1) * BUF;
        s16x8 bh[4], bl[4];
        #pragma unroll
        for (int ni = 0; ni < 4; ++ni) {
            int br = wn * 64 + ni * 16 + frow;
            int pc = kblk ^ ((br >> 1) & 3);
            bh[ni] = *(const s16x8*)&cb[WOFF * 4096 + br * 32 + pc * 8];
            bl[ni] = *(const s16x8*)&cb[(WOFF + 1) * 4096 + br * 32 + pc * 8];
        }
        #pragma unroll
        for (int mi = 0; mi < 4; ++mi) {
            int ar = wm * 64 + mi * 16 + frow;
            int pc = kblk ^ ((ar >> 1) & 3);
            s16x8 ah = *(const s16x8*)&cb[0 * 4096 + ar * 32 + pc * 8];
            s16x8 al;
            if (NPROD == 3) al = *(const s16x8*)&cb[1 * 4096 + ar * 32 + pc * 8];
            #pragma unroll
            for (int ni = 0; ni < 4; ++ni) {
                acc[mi][ni] = __builtin_amdgcn_mfma_f32_16x16x32_bf16(ah, bh[ni], acc[mi][ni], 0, 0, 0);
                acc[mi][ni] = __builtin_amdgcn_mfma_f32_16x16x32_bf16(ah, bl[ni], acc[mi][ni], 0, 0, 0);
                if (NPROD == 3)
                    acc[mi][ni] = __builtin_amdgcn_mfma_f32_16x16x32_bf16(al, bh[ni], acc[mi][ni], 0, 0, 0);
            }
        }
    }
}

// ---------------- split-bf16 MFMA GEMM:  C = act(A @ W^T + bias) ----------------
template<int ACTF, int WF32, int WSPLIT, int PARTIAL, int NPROD>
__global__ __launch_bounds__(256)
void gemm_mfma_k(const u16* __restrict__ Ah, const u16* __restrict__ Al,
                 const u16* __restrict__ Wh, const u16* __restrict__ Wl,
                 float* __restrict__ C, u16* __restrict__ Chi, u16* __restrict__ Clo,
                 int M, int N, int K, const float* __restrict__ bias, int cmaj)
{
    constexpr int TILES = (NPROD == 3) ? 4 : 3;
    __shared__ u16 lds[2 * TILES * 4096];
    const int tid = threadIdx.x;
    const int lane = tid & 63, wid = tid >> 6;
    const int wm = wid >> 1, wn = wid & 1;
    int bx, by; xcd_swz2(cmaj, bx, by);
    const int row0 = by * 128, col0 = bx * 128;
    const u16* sp = (wid == 0) ? Ah : (wid == 1) ? Al : (wid == 2) ? Wh : Wl;
    const int rbase = (wid < 2) ? row0 : col0;
    const int clampM = (wid < 2) ? 1 : 0;
    f32x4 acc[4][4] = {};
    int kbeg = 0, kend = K;
    if (PARTIAL) {
        int Kseg = K / gridDim.z;
        kbeg = blockIdx.z * Kseg;
        kend = kbeg + Kseg;
    }
    mm_loop32<NPROD>(&lds[0], sp, rbase, M, clampM, K, kbeg, kend, wid, lane, wm, wn, acc);

    const int erow = (lane >> 4) * 4, ecol = lane & 15;
    #pragma unroll
    for (int mi = 0; mi < 4; ++mi) {
        #pragma unroll
        for (int ni = 0; ni < 4; ++ni) {
            int c = col0 + wn * 64 + ni * 16 + ecol;
            float bv = (!PARTIAL && bias) ? bias[c] : 0.f;
            #pragma unroll
            for (int reg = 0; reg < 4; ++reg) {
                int r = row0 + wm * 64 + mi * 16 + erow + reg;
                if (r >= M) continue;
                float v = acc[mi][ni][reg] + bv;
                if (PARTIAL) {
                    C[((size_t)blockIdx.z * M + r) * N + c] = v;
                    continue;
                }
                if (ACTF == 1) v = v / (1.f + __expf(-v));
                else if (ACTF == 2) {
                    float u = 0.7978845608028654f * (v + 0.044715f * v * v * v);
                    v = 0.5f * v * (1.f + tanhf(u));
                }
                size_t o = (size_t)r * N + c;
                if (WF32) C[o] = v;
                if (WSPLIT) { u16 h, l; split2(v, h, l); Chi[o] = h; Clo[o] = l; }
            }
        }
    }
}

// fused qkv GEMM (2-product, 3-tile LDS): Q hi, kc hi, kcT split, V f32
__global__ __launch_bounds__(256)
void gemm_qkv_k(const u16* __restrict__ Ah, const u16* __restrict__ Al,
                const u16* __restrict__ Wh, const u16* __restrict__ Wl,
                u16* __restrict__ Qh, u16* __restrict__ Ql,
                u16* __restrict__ kch, u16* __restrict__ kcl,
                u16* __restrict__ kcTh, u16* __restrict__ kcTl,
                float* __restrict__ Vb, int M, int N, int K)
{
    __shared__ u16 lds[2 * 3 * 4096];
    const int tid = threadIdx.x;
    const int lane = tid & 63, wid = tid >> 6;
    const int wm = wid >> 1, wn = wid & 1;
    int bx, by; xcd_swz2(1, bx, by);
    const int row0 = by * 128, col0 = bx * 128;
    const u16* sp = (wid == 0) ? Ah : (wid == 1) ? Al : (wid == 2) ? Wh : Wl;
    const int rbase = (wid < 2) ? row0 : col0;
    f32x4 acc[4][4] = {};
    mm_loop32<2>(&lds[0], sp, rbase, M, 0, K, 0, K, wid, lane, wm, wn, acc);

    const int erow = (lane >> 4) * 4, ecol = lane & 15;
    #pragma unroll
    for (int mi = 0; mi < 4; ++mi) {
        #pragma unroll
        for (int ni = 0; ni < 4; ++ni) {
            int c = col0 + wn * 64 + ni * 16 + ecol;
            #pragma unroll
            for (int reg = 0; reg < 4; ++reg) {
                int r = row0 + wm * 64 + mi * 16 + erow + reg;
                float v = acc[mi][ni][reg];
                int b = r >> 10, t = r & 1023;
                if (c < 1024) {
                    size_t o = (size_t)r * 1024 + c;
                    Qh[o] = f2bf(v);
                } else if (c < 2048) {
                    int d = c - 1024;
                    int ch = t >> 7, rr = t & 127;
                    size_t o = ((size_t)((ch * 2 + b) * 128 + rr)) * 1024 + d;
                    u16 h, l; split2(v, h, l);
                    kch[o] = h;
                    size_t ot = (size_t)ch * 262144 + (size_t)d * 256 + b * 128 + rr;
                    kcTh[ot] = h; kcTl[ot] = l;
                } else {
                    int d = c - 2048;
                    int ch = t >> 7, rr = t & 127;
                    Vb[((size_t)((ch * 2 + b) * 128 + rr)) * 1024 + d] = v;
                }
            }
        }
    }
}

// fused attention-qkv GEMM (2-product, 3-tile LDS): fQ hi (0.125-scaled),
// fK split, fV^T hi
__global__ __launch_bounds__(256)
void gemm_aqkv_k(const u16* __restrict__ Ah, const u16* __restrict__ Al,
                 const u16* __restrict__ Wh, const u16* __restrict__ Wl,
                 u16* __restrict__ fQh,
                 u16* __restrict__ fKh, u16* __restrict__ fKl,
                 u16* __restrict__ fVt, int M, int N, int K)
{
    __shared__ u16 lds[2 * 3 * 4096];
    const int tid = threadIdx.x;
    const int lane = tid & 63, wid = tid >> 6;
    const int wm = wid >> 1, wn = wid & 1;
    int bx, by; xcd_swz2(1, bx, by);
    // dead Q tiles: cols<1024 only used for query rows n>=1040
    if (bx < 8 && ((by <= 7) || (by >= 17 && by <= 23))) return;
    const int row0 = by * 128, col0 = bx * 128;
    const u16* sp = (wid == 0) ? Ah : (wid == 1) ? Al : (wid == 2) ? Wh : Wl;
    const int rbase = (wid < 2) ? row0 : col0;
    const int clampM = (wid < 2) ? 1 : 0;
    f32x4 acc[4][4] = {};
    mm_loop32<2>(&lds[0], sp, rbase, M, clampM, K, 0, K, wid, lane, wm, wn, acc);

    const int erow = (lane >> 4) * 4, ecol = lane & 15;
    #pragma unroll
    for (int mi = 0; mi < 4; ++mi) {
        #pragma unroll
        for (int ni = 0; ni < 4; ++ni) {
            int c = col0 + wn * 64 + ni * 16 + ecol;
            #pragma unroll
            for (int reg = 0; reg < 4; ++reg) {
                int r = row0 + wm * 64 + mi * 16 + erow + reg;
                if (r >= M) continue;
                float v = acc[mi][ni][reg];
                int b = (r >= 2064) ? 1 : 0;
                int n = r - b * 2064;
                if (c < 1024) {
                    if (n >= NPERS + TSEQ) {
                        int h = c >> 6, d = c & 63;
                        int row = n - (NPERS + TSEQ);
                        size_t o = (((size_t)(b * 16 + h)) * 1024 + row) * 64 + d;
                        fQh[o] = f2bf(0.125f * v);
                    }
                } else if (c < 2048) {
                    int cc = c - 1024;
                    int h = cc >> 6, d = cc & 63;
                    size_t o = (((size_t)(b * 16 + h)) * NTOK + n) * 64 + d;
                    u16 hh, ll; split2(v, hh, ll);
                    fKh[o] = hh; fKl[o] = ll;
                } else {
                    int cc = c - 2048;
                    int h = cc >> 6, d = cc & 63;
                    fVt[(((size_t)(b * 16 + h)) * 64 + d) * NTOK + n] = f2bf(v);
                }
            }
        }
    }
}

// split-K reduce + epilogue
template<int ACTF, int WF32, int WSPLIT>
__global__ __launch_bounds__(256)
void reduce_k(const float* __restrict__ Cp, int S,
              float* __restrict__ C, u16* __restrict__ Chi, u16* __restrict__ Clo,
              const float* __restrict__ bias, int M, int N)
{
    int i = blockIdx.x * 256 + threadIdx.x;
    int n4 = (int)((size_t)M * N / 4);
    if (i >= n4) return;
    size_t off = (size_t)i * 4;
    float4 v = *(const float4*)&Cp[off];
    for (int z = 1; z < S; ++z) {
        float4 u = *(const float4*)&Cp[(size_t)z * M * N + off];
        v.x += u.x; v.y += u.y; v.z += u.z; v.w += u.w;
    }
    int c = (int)(off % N);
    float vv[4] = {v.x, v.y, v.z, v.w};
    #pragma unroll
    for (int j = 0; j < 4; ++j) {
        float w = vv[j];
        if (bias) w += bias[c + j];
        if (ACTF == 1) w = w / (1.f + __expf(-w));
        else if (ACTF == 2) {
            float u = 0.7978845608028654f * (w + 0.044715f * w * w * w);
            w = 0.5f * w * (1.f + tanhf(u));
        }
        if (WF32) C[off + j] = w;
        if (WSPLIT) { u16 h, l; split2(w, h, l); Chi[off + j] = h; Clo[off + j] = l; }
    }
}

// memtok reduce: sum S=2 partials + b2, write split DIRECTLY into token rows
__global__ __launch_bounds__(256)
void reduce_tok_k(const float* __restrict__ Cp, const float* __restrict__ bias,
                  u16* __restrict__ th, u16* __restrict__ tl)
{
    int i = blockIdx.x * 256 + threadIdx.x;
    if (i >= 524288) return;
    size_t off = (size_t)i * 4;
    float4 v = *(const float4*)&Cp[off];
    float4 u = *(const float4*)&Cp[2097152 + off];
    v.x += u.x; v.y += u.y; v.z += u.z; v.w += u.w;
    int r = (int)(off >> 10), c = (int)(off & 1023);
    int b = r >> 10, t = r & 1023;
    size_t orow = (((size_t)(b * NTOK + NPERS + t)) << 10) + c;
    float vv[4] = {v.x + bias[c], v.y + bias[c + 1], v.z + bias[c + 2], v.w + bias[c + 3]};
    u16 h0,l0,h1,l1,h2,l2,h3,l3;
    split2(vv[0],h0,l0); split2(vv[1],h1,l1); split2(vv[2],h2,l2); split2(vv[3],h3,l3);
    ushort4 hv = {h0,h1,h2,h3}, lv = {l0,l1,l2,l3};
    *(ushort4*)&th[orow] = hv;
    *(ushort4*)&tl[orow] = lv;
}

static void gemm_mfma(hipStream_t s, int act, int wf32, int wsplit,
                      const u16* Ah, const u16* Al, const u16* Wh, const u16* Wl,
                      float* C, u16* Ch, u16* Cl, int M, int N, int K,
                      const float* bias, int nprod = 3, int cmaj = 0)
{
    dim3 g(N / 128, (M + 127) / 128), b(256);
    if (act == 0 && wf32 == 1 && wsplit == 0)
        gemm_mfma_k<0,1,0,0,3><<<g,b,0,s>>>(Ah,Al,Wh,Wl,C,Ch,Cl,M,N,K,bias,cmaj);
    else if (act == 0 && wf32 == 1 && wsplit == 1)
        gemm_mfma_k<0,1,1,0,3><<<g,b,0,s>>>(Ah,Al,Wh,Wl,C,Ch,Cl,M,N,K,bias,cmaj);
    else if (act == 0 && wf32 == 0 && wsplit == 1)
        gemm_mfma_k<0,0,1,0,3><<<g,b,0,s>>>(Ah,Al,Wh,Wl,C,Ch,Cl,M,N,K,bias,cmaj);
    else if (act == 1)
        gemm_mfma_k<1,0,1,0,3><<<g,b,0,s>>>(Ah,Al,Wh,Wl,C,Ch,Cl,M,N,K,bias,cmaj);
    else if (nprod == 2)
        gemm_mfma_k<2,0,1,0,2><<<g,b,0,s>>>(Ah,Al,Wh,Wl,C,Ch,Cl,M,N,K,bias,cmaj);
    else
        gemm_mfma_k<2,0,1,0,3><<<g,b,0,s>>>(Ah,Al,Wh,Wl,C,Ch,Cl,M,N,K,bias,cmaj);
}

static void gemm_mfma_sk(hipStream_t s, int act, int wf32, int wsplit,
                         const u16* Ah, const u16* Al, const u16* Wh, const u16* Wl,
                         float* C, u16* Ch, u16* Cl, int M, int N, int K,
                         const float* bias, int S, float* part, int nprod = 3,
                         int cmaj = 0)
{
    if (S <= 1) { gemm_mfma(s, act, wf32, wsplit, Ah, Al, Wh, Wl, C, Ch, Cl, M, N, K, bias, nprod, cmaj); return; }
    dim3 g(N / 128, (M + 127) / 128, S), b(256);
    if (nprod == 2)
        gemm_mfma_k<0,0,0,1,2><<<g,b,0,s>>>(Ah,Al,Wh,Wl,part,nullptr,nullptr,M,N,K,nullptr,cmaj);
    else
        gemm_mfma_k<0,0,0,1,3><<<g,b,0,s>>>(Ah,Al,Wh,Wl,part,nullptr,nullptr,M,N,K,nullptr,cmaj);
    int n4 = (int)((size_t)M * N / 4);
    dim3 rg((n4 + 255) / 256), rb(256);
    if (act == 0 && wf32 == 1 && wsplit == 0)
        reduce_k<0,1,0><<<rg,rb,0,s>>>(part, S, C, Ch, Cl, bias, M, N);
    else if (act == 0 && wf32 == 1 && wsplit == 1)
        reduce_k<0,1,1><<<rg,rb,0,s>>>(part, S, C, Ch, Cl, bias, M, N);
    else if (act == 0 && wf32 == 0 && wsplit == 1)
        reduce_k<0,0,1><<<rg,rb,0,s>>>(part, S, C, Ch, Cl, bias, M, N);
    else if (act == 1)
        reduce_k<1,0,1><<<rg,rb,0,s>>>(part, S, C, Ch, Cl, bias, M, N);
    else
        reduce_k<2,0,1><<<rg,rb,0,s>>>(part, S, C, Ch, Cl, bias, M, N);
}

// ---------------- scan-specialized split-bf16 MFMA GEMM body (BK=64 dbuf) -------
// NPROD=2: drops A-low product (gradient-class 2^-9 rel err); 3 tiles/buffer,
// 96 KB LDS, wave 1 skips staging. W operands keep full hi+lo splits.
template<int MODE, int NPROD>
__device__ __forceinline__ void scan_body(u16* lds, int bx, int by,
                 const u16* __restrict__ Ah, const u16* __restrict__ Al,
                 const u16* __restrict__ Wh, const u16* __restrict__ Wl,
                 float* __restrict__ C, u16* __restrict__ Chi, u16* __restrict__ Clo,
                 u16* __restrict__ ChiT, u16* __restrict__ CloT,
                 const float* __restrict__ Zf, const float* __restrict__ add,
                 const float* __restrict__ bias, float* __restrict__ CP,
                 int M, int N, int K, float alpha)
{
    constexpr int TILES = (NPROD == 3) ? 4 : 3;
    constexpr int BUF = TILES * 8192;
    constexpr int WOFF = (NPROD == 3) ? 2 : 1;
    const int tid = threadIdx.x;
    const int lane = tid & 63, wid = tid >> 6;
    const int wm = wid >> 1, wn = wid & 1;
    const int row0 = by * 128, col0 = bx * 128;

    const u16* sp = (wid == 0) ? Ah : (wid == 1) ? Al : (wid == 2) ? Wh : Wl;
    const int rbase = (wid < 2) ? row0 : col0;
    const int doStage = (NPROD == 3) || (wid != 1);
    const int stile = (NPROD == 3) ? wid : ((wid == 0) ? 0 : wid - 1);

    f32x4 acc[4][4] = {};
    const int frow = lane & 15, kblk = lane >> 4;
    const int nt = K >> 6;

    if (doStage) stage_tile64(sp, lds + stile * 8192, rbase, K, 0, lane);

    for (int t = 0; t < nt; ++t) {
        __syncthreads();
        if (t + 1 < nt && doStage)
            stage_tile64(sp, lds + ((t + 1) & 1) * BUF + stile * 8192, rbase, K,
                         (t + 1) << 6, lane);
        const u16* cb = lds + (t & 1) * BUF;

        #pragma unroll
        for (int s = 0; s < 2; ++s) {
            s16x8 bh[4], bl[4];
            #pragma unroll
            for (int ni = 0; ni < 4; ++ni) {
                int br = wn * 64 + ni * 16 + frow;
                int pc = (s * 4 + kblk) ^ (br & 7);
                bh[ni] = *(const s16x8*)&cb[WOFF * 8192 + br * 64 + pc * 8];
                bl[ni] = *(const s16x8*)&cb[(WOFF + 1) * 8192 + br * 64 + pc * 8];
            }
            #pragma unroll
            for (int mi = 0; mi < 4; ++mi) {
                int ar = wm * 64 + mi * 16 + frow;
                int pc = (s * 4 + kblk) ^ (ar & 7);
                s16x8 ah = *(const s16x8*)&cb[0 * 8192 + ar * 64 + pc * 8];
                s16x8 al;
                if (NPROD == 3) al = *(const s16x8*)&cb[1 * 8192 + ar * 64 + pc * 8];
                #pragma unroll
                for (int ni = 0; ni < 4; ++ni) {
                    acc[mi][ni] = __builtin_amdgcn_mfma_f32_16x16x32_bf16(ah, bh[ni], acc[mi][ni], 0, 0, 0);
                    acc[mi][ni] = __builtin_amdgcn_mfma_f32_16x16x32_bf16(ah, bl[ni], acc[mi][ni], 0, 0, 0);
                    if (NPROD == 3)
                        acc[mi][ni] = __builtin_amdgcn_mfma_f32_16x16x32_bf16(al, bh[ni], acc[mi][ni], 0, 0, 0);
                }
            }
        }
    }

    const int erow = (lane >> 4) * 4, ecol = lane & 15;
    float csum[4] = {0.f, 0.f, 0.f, 0.f};
    #pragma unroll
    for (int mi = 0; mi < 4; ++mi) {
        #pragma unroll
        for (int ni = 0; ni < 4; ++ni) {
            int c = col0 + wn * 64 + ni * 16 + ecol;
            #pragma unroll
            for (int reg = 0; reg < 4; ++reg) {
                int r = row0 + wm * 64 + mi * 16 + erow + reg;
                float v = acc[mi][ni][reg];
                size_t o = (size_t)r * N + c;
                if (MODE == 1) {
                    v += bias[c];
                    C[o] = v;
                    float hv = v / (1.f + __expf(-v));
                    u16 h, l; split2(hv, h, l);
                    Chi[o] = h; Clo[o] = l;
                    size_t ot = (size_t)c * M + r;
                    ChiT[ot] = h; CloT[ot] = l;
                } else if (MODE == 2) {
                    v += bias[c] - add[o];
                    u16 h, l; split2(v, h, l);
                    Chi[o] = h; Clo[o] = l;
                    size_t ot = (size_t)c * M + r;
                    ChiT[ot] = h; CloT[ot] = l;
                    csum[ni] += v;
                } else if (MODE == 3) {
                    C[o] = alpha * v;
                } else {
                    v *= alpha;
                    float z = Zf[o];
                    float sg = 1.f / (1.f + __expf(-z));
                    v *= sg * (1.f + z * (1.f - sg));
                    u16 h, l; split2(v, h, l);
                    size_t ot = (size_t)c * M + r;
                    ChiT[ot] = h; CloT[ot] = l;
                    csum[ni] += v;
                }
            }
        }
    }
    if (MODE == 2 || MODE == 4) {
        #pragma unroll
        for (int ni = 0; ni < 4; ++ni) {
            float s = csum[ni];
            s += __shfl_xor(s, 16);
            s += __shfl_xor(s, 32);
            if ((lane >> 4) == 0) {
                int c = col0 + wn * 64 + ni * 16 + ecol;
                float w = (MODE == 2) ? alpha * s : s;
                CP[(size_t)(by * 2 + wm) * N + c] = w;
            }
        }
    }
}

template<int MODE>
__global__ __launch_bounds__(256)
void gemm_scan_k(const u16* __restrict__ Ah, const u16* __restrict__ Al,
                 const u16* __restrict__ Wh, const u16* __restrict__ Wl,
                 float* __restrict__ C, u16* __restrict__ Chi, u16* __restrict__ Clo,
                 u16* __restrict__ ChiT, u16* __restrict__ CloT,
                 const float* __restrict__ Zf, const float* __restrict__ add,
                 const float* __restrict__ bias, float* __restrict__ CP,
                 int M, int N, int K, float alpha)
{
    __shared__ u16 lds[2 * 3 * 8192];       // 96 KB (2-product)
    int bx, by; xcd_swizzle(bx, by);
    scan_body<MODE, 2>(&lds[0], bx, by, Ah, Al, Wh, Wl, C, Chi, Clo, ChiT, CloT,
                       Zf, add, bias, CP, M, N, K, alpha);
}

// merged launch: gW2 (MODE3, 4x8 tiles at by<8) || dh (MODE4, 4x2 tiles at by>=8)
__global__ __launch_bounds__(256)
void gemm_scan_pair_k(const u16* __restrict__ rTh, const u16* __restrict__ rTl,
                      const u16* __restrict__ hTh, const u16* __restrict__ hTl,
                      float* __restrict__ gW2,
                      const u16* __restrict__ rh_, const u16* __restrict__ rl_,
                      const u16* __restrict__ w2th, const u16* __restrict__ w2tl,
                      u16* __restrict__ dhTh, u16* __restrict__ dhTl,
                      const float* __restrict__ z1, float* __restrict__ cp1, float cs)
{
    __shared__ u16 lds[2 * 3 * 8192];       // 96 KB (2-product)
    if (blockIdx.y < 8) {
        scan_body<3, 2>(&lds[0], blockIdx.x, blockIdx.y, rTh, rTl, hTh, hTl,
                        gW2, nullptr, nullptr, nullptr, nullptr, nullptr, nullptr,
                        nullptr, nullptr, 1024, 512, 256, cs);
    } else {
        scan_body<4, 2>(&lds[0], blockIdx.x, blockIdx.y - 8, rh_, rl_, w2th, w2tl,
                        nullptr, nullptr, nullptr, dhTh, dhTl, z1, nullptr,
                        nullptr, cp1, 256, 512, 1024, cs);
    }
}

// ---------------- small kernels ----------------
__global__ void cvt_split_k(const float* __restrict__ in, u16* __restrict__ hi,
                            u16* __restrict__ lo, int n4) {
    int i = blockIdx.x * 256 + threadIdx.x;
    if (i >= n4) return;
    float4 v = *(const float4*)&in[(size_t)i * 4];
    u16 h0,l0,h1,l1,h2,l2,h3,l3;
    split2(v.x,h0,l0); split2(v.y,h1,l1); split2(v.z,h2,l2); split2(v.w,h3,l3);
    ushort4 hv = {h0,h1,h2,h3}, lv = {l0,l1,l2,l3};
    *(ushort4*)&hi[(size_t)i * 4] = hv;
    *(ushort4*)&lo[(size_t)i * 4] = lv;
}
__global__ void transpose_split_k(const float* __restrict__ in, u16* __restrict__ outh,
                                  u16* __restrict__ outl, int R, int C) {
    __shared__ float t[32][33];
    const int c0 = blockIdx.x * 32, r0 = blockIdx.y * 32;
    const size_t zoff = (size_t)blockIdx.z * R * C;
    const int tx = threadIdx.x & 31, ty = threadIdx.x >> 5;
    #pragma unroll
    for (int p = 0; p < 4; ++p) {
        int r = ty + p * 8;
        t[r][tx] = in[zoff + (size_t)(r0 + r) * C + c0 + tx];
    }
    __syncthreads();
    #pragma unroll
    for (int p = 0; p < 4; ++p) {
        int cc = ty + p * 8;
        float v = t[tx][cc];
        u16 h, l; split2(v, h, l);
        size_t o = zoff + (size_t)(c0 + cc) * R + r0 + tx;
        outh[o] = h; outl[o] = l;
    }
}
__global__ void update3_k(float* __restrict__ p, float* __restrict__ mo,
                          const float* __restrict__ g,
                          const float* __restrict__ cp1, const float* __restrict__ cp2,
                          u16* __restrict__ w1h, u16* __restrict__ w1l,
                          u16* __restrict__ w2h, u16* __restrict__ w2l,
                          u16* __restrict__ w2th, u16* __restrict__ w2tl, int n) {
    int i = blockIdx.x * 256 + threadIdx.x;
    if (i >= n) return;
    float gi;
    if (i < 524288) gi = g[i];
    else if (i < 524800) {
        int j = i - 524288;
        gi = cp1[j] + cp1[512 + j] + cp1[1024 + j] + cp1[1536 + j];
    } else if (i < 1049088) gi = g[i];
    else {
        int j = i - 1049088;
        gi = cp2[j] + cp2[1024 + j] + cp2[2048 + j] + cp2[3072 + j];
    }
    float m = ETA_C * mo[i] - THETA_C * gi;
    mo[i] = m;
    float pv = (1.f - ALPHA_C) * p[i] + m;
    p[i] = pv;
    if (i < 524288) {
        u16 h, l; split2(pv, h, l); w1h[i] = h; w1l[i] = l;
    } else if (i >= 524800 && i < 1049088) {
        int j = i - 524800;
        u16 h, l; split2(pv, h, l);
        w2h[j] = h; w2l[j] = l;
        int tj = (j & 511) * 1024 + (j >> 9);
        w2th[tj] = h; w2tl[tj] = l;
    }
}
// fill ONLY persist (P) and x rows of the token split buffers
__global__ void tokens_px_k(const float* __restrict__ P, const float* __restrict__ x,
                            u16* __restrict__ th, u16* __restrict__ tl) {
    size_t idx = (size_t)blockIdx.x * 256 + threadIdx.x;   // 2*1040*1024
    if (idx >= (size_t)2 * 1040 * 1024) return;
    int d = (int)(idx & 1023);
    int rl = (int)((idx >> 10) % 1040);
    int b = (int)(idx / ((size_t)1040 * 1024));
    float v; int n;
    if (rl < NPERS) { v = P[(size_t)rl * 1024 + d]; n = rl; }
    else { int t = rl - NPERS; v = x[((size_t)b * TSEQ + t) * 1024 + d]; n = NPERS + TSEQ + t; }
    size_t o = (((size_t)(b * NTOK + n)) << 10) + d;
    u16 h, l; split2(v, h, l); th[o] = h; tl[o] = l;
}
__global__ void mul_k(const float* __restrict__ a, const float* __restrict__ b,
                      float* __restrict__ o, int n) {
    int i = blockIdx.x * 256 + threadIdx.x;
    if (i < n) o[i] = a[i] * b[i];
}

// ---------------- MFMA flash attention: split-KV partial + merge ----------------
// Fixed-shift softmax (m == 0). P hi-only; Q hi-only (2-product QK^T, K split kept).
// Row-sum l via ones-column MFMA.
__global__ __launch_bounds__(256)
void flash_part_k(const u16* __restrict__ Qsh,
                  const u16* __restrict__ Ksh, const u16* __restrict__ Ksl,
                  const u16* __restrict__ Vts, float* __restrict__ Of,
                  float* __restrict__ Lf)
{
    __shared__ u16 lds[16384];             // KH KL VT | PH = 32 KB
    u16* KH = lds;            u16* KL = lds + 4096;
    u16* VT = lds + 8192;
    u16* PH = lds + 12288;

    int lid = blockIdx.x + (blockIdx.y << 4) + (blockIdx.z << 8);
    int t1024 = ((lid & 7) << 7) | (lid >> 3);
    const int qt = t1024 & 15, h = (t1024 >> 4) & 15;
    const int zb = t1024 >> 8;
    const int b = zb >> 1, z = zb & 1;

    const int tid = threadIdx.x;
    const int lane = tid & 63, wid = tid >> 6;
    const int fr = lane & 15, kq = lane >> 4;
    const int bh = b * 16 + h;
    const int q0c = qt * 64;
    const int q0a = NPERS + TSEQ + q0c;
    const int ntile = ((q0a + 63) >> 6) + 1;
    const int half = ntile >> 1;
    const int jt0 = z ? half : 0;
    const int jt1 = z ? ntile : half;
    const int l8 = lane & 7, lr8 = lane >> 3;

    auto stageKV = [&](int jt) {
        const int j0 = jt * 64;
        #pragma unroll
        for (int jj = 0; jj < 6; ++jj) {
            int j = wid * 6 + jj;
            int buf = j >> 3, i8 = j & 7;
            if (buf < 2) {
                int row = i8 * 8 + lr8;
                int grow = j0 + row; if (grow > NTOK - 1) grow = NTOK - 1;
                int c = l8 ^ (row & 7);
                const u16* src = (buf == 0 ? Ksh : Ksl) +
                                 (((size_t)bh * NTOK + grow) << 6) + c * 8;
                gload_lds16(src, (buf == 0 ? KH : KL) + i8 * 512);
            } else {
                int d = i8 * 8 + lr8;
                int c = l8 ^ (d & 7);
                int col = j0 + c * 8; if (col > NTOK - 8) col = NTOK - 8;
                const u16* src = Vts + ((size_t)bh * 64 + d) * NTOK + col;
                gload_lds16(src, VT + i8 * 512);
            }
        }
    };

    // Q fragments direct from global (hi only)
    s16x8 qh[2];
    {
        const size_t qrow = ((size_t)bh * 1024 + q0c + wid * 16 + fr) << 6;
        #pragma unroll
        for (int kb = 0; kb < 2; ++kb)
            qh[kb] = *(const s16x8*)&Qsh[qrow + (size_t)(kb * 4 + kq) * 8];
    }

    // ones fragment (bf16 1.0) for the l row-sum MFMA
    s16x8 ones;
    #pragma unroll
    for (int i = 0; i < 8; ++i) ones[i] = (short)0x3F80;

    f32x4 Oa[4] = {};
    f32x4 lacc = {};

    for (int jt = jt0; jt < jt1; ++jt) {
        const int j0 = jt * 64;
        stageKV(jt);
        __syncthreads();                    // KV landed

        f32x4 sacc[4] = {};
        __builtin_amdgcn_s_setprio(1);
        #pragma unroll
        for (int nt = 0; nt < 4; ++nt) {
            #pragma unroll
            for (int kb = 0; kb < 2; ++kb) {
                int br = nt * 16 + fr;
                int sl = (kb * 4 + kq) ^ (fr & 7);
                s16x8 kh = *(const s16x8*)&KH[br * 64 + sl * 8];
                s16x8 kl = *(const s16x8*)&KL[br * 64 + sl * 8];
                sacc[nt] = __builtin_amdgcn_mfma_f32_16x16x32_bf16(qh[kb], kh, sacc[nt], 0, 0, 0);
                sacc[nt] = __builtin_amdgcn_mfma_f32_16x16x32_bf16(qh[kb], kl, sacc[nt], 0, 0, 0);
            }
        }
        __builtin_amdgcn_s_setprio(0);

        // fixed-shift softmax: p = exp(s) masked, store bf16-hi only
        #pragma unroll
        for (int r = 0; r < 4; ++r) {
            const int qloc = kq * 4 + r;
            const int qi = q0a + wid * 16 + qloc;
            const int prow = wid * 16 + qloc;
            #pragma unroll
            for (int nt = 0; nt < 4; ++nt) {
                int kj = j0 + nt * 16 + fr;
                float e = (kj <= qi) ? __expf(sacc[nt][r]) : 0.f;
                int col = nt * 16 + fr;
                int sl = (col >> 3) ^ (qloc & 7);
                PH[prow * 64 + sl * 8 + (col & 7)] = f2bf(e);
            }
        }

        // PV + l row-sum (ones column) on the matrix pipe
        __builtin_amdgcn_s_setprio(1);
        #pragma unroll
        for (int kb = 0; kb < 2; ++kb) {
            int pr = wid * 16 + fr;
            int sl = (kb * 4 + kq) ^ (fr & 7);
            s16x8 pa = *(const s16x8*)&PH[pr * 64 + sl * 8];
            lacc = __builtin_amdgcn_mfma_f32_16x16x32_bf16(pa, ones, lacc, 0, 0, 0);
            #pragma unroll
            for (int dt = 0; dt < 4; ++dt) {
                int vr = dt * 16 + fr;
                s16x8 vb = *(const s16x8*)&VT[vr * 64 + sl * 8];
                Oa[dt] = __builtin_amdgcn_mfma_f32_16x16x32_bf16(pa, vb, Oa[dt], 0, 0, 0);
            }
        }
        __builtin_amdgcn_s_setprio(0);
        __syncthreads();                    // compute done before next stage overwrites
    }

    const size_t obase = ((((size_t)z * 2 + b) * 16 + h) * 16 + qt) * 4096;
    const size_t mlb   = ((((size_t)z * 2 + b) * 16 + h) * 16 + qt) * 64;
    #pragma unroll
    for (int r = 0; r < 4; ++r) {
        int rl = wid * 16 + kq * 4 + r;
        if (fr == 0) Lf[mlb + rl] = lacc[r];
        #pragma unroll
        for (int dt = 0; dt < 4; ++dt)
            Of[obase + (size_t)rl * 64 + dt * 16 + fr] = Oa[dt][r];
    }
}

// merge: O = (O0 + O1) / (l0 + l1)
__global__ __launch_bounds__(256)
void flash_merge_k(const float* __restrict__ Of, const float* __restrict__ Lf,
                   u16* __restrict__ oh, u16* __restrict__ ol)
{
    const int qt = blockIdx.x, h = blockIdx.y, b = blockIdx.z;
    const int tid = threadIdx.x;
    const int row = tid >> 2, quad = tid & 3;
    const size_t b0 = ((((size_t)0 * 2 + b) * 16 + h) * 16 + qt) * 4096 + (size_t)row * 64;
    const size_t b1 = ((((size_t)1 * 2 + b) * 16 + h) * 16 + qt) * 4096 + (size_t)row * 64;
    const size_t m0i = ((((size_t)0 * 2 + b) * 16 + h) * 16 + qt) * 64 + row;
    const size_t m1i = ((((size_t)1 * 2 + b) * 16 + h) * 16 + qt) * 64 + row;
    float inv = 1.f / (Lf[m0i] + Lf[m1i]);
    const size_t orow = ((size_t)(b * 1024 + qt * 64 + row)) * 1024 + h * 64;
    #pragma unroll
    for (int i = 0; i < 4; ++i) {
        int col = quad * 16 + i * 4;
        float4 v0 = *(const float4*)&Of[b0 + col];
        float4 v1 = *(const float4*)&Of[b1 + col];
        float o0 = (v0.x + v1.x) * inv;
        float o1 = (v0.y + v1.y) * inv;
        float o2 = (v0.z + v1.z) * inv;
        float o3 = (v0.w + v1.w) * inv;
        u16 h0,l0_,h1,l1_,h2,l2_,h3,l3_;
        split2(o0,h0,l0_); split2(o1,h1,l1_); split2(o2,h2,l2_); split2(o3,h3,l3_);
        ushort4 hv = {h0,h1,h2,h3}, lv = {l0_,l1_,l2_,l3_};
        *(ushort4*)&oh[orow + col] = hv;
        *(ushort4*)&ol[orow + col] = lv;
    }
}

// ---------------- launch ----------------
extern "C" void kernel_launch(void* const* d_in, const int* in_sizes, int n_in,
                              void* d_out, int out_size, void* d_ws, size_t ws_size,
                              hipStream_t stream)
{
    const float* x     = (const float*)d_in[0];
    const float* Wqkv  = (const float*)d_in[1];
    const float* mW1   = (const float*)d_in[2];
    const float* mb1   = (const float*)d_in[3];
    const float* mW2   = (const float*)d_in[4];
    const float* mb2   = (const float*)d_in[5];
    const float* Pp    = (const float*)d_in[6];
    const float* Wqa   = (const float*)d_in[7];
    const float* Wo    = (const float*)d_in[8];
    const float* ffW1  = (const float*)d_in[9];
    const float* ffb1  = (const float*)d_in[10];
    const float* ffW2  = (const float*)d_in[11];
    const float* ffb2  = (const float*)d_in[12];
    char* wsb = (char*)d_ws;
    float* outp = (float*)d_out;

    // region A (multiplexed)
    float* z1    = (float*)(wsb + oRA);
    float* grd   = (float*)(wsb + oRA + 3145728);
    float* cp2   = (float*)(wsb + oRA + 7346176);
    float* cp1   = (float*)(wsb + oRA + 7362560);
    u16* hh_     = (u16*)(wsb + oRA + 8388608);
    u16* hl_     = (u16*)(wsb + oRA + 8650752);
    u16* hTh     = (u16*)(wsb + oRA + 9437184);
    u16* hTl     = (u16*)(wsb + oRA + 9699328);
    u16* rh_     = (u16*)(wsb + oRA + 10485760);
    u16* rl_     = (u16*)(wsb + oRA + 11010048);
    u16* rTh     = (u16*)(wsb + oRA + 11534336);
    u16* rTl     = (u16*)(wsb + oRA + 12058624);
    u16* dhTh    = (u16*)(wsb + oRA + 12582912);
    u16* dhTl    = (u16*)(wsb + oRA + 12845056);
    u16* kcTh    = (u16*)(wsb + oRA + 16777216);
    u16* kcTl    = (u16*)(wsb + oRA + 20971520);
    // flash partials + attn operands (region A dead between scan and FFN)
    float* Of    = (float*)(wsb + oRA);                   // 16.78 MB
    float* Lf    = (float*)(wsb + oRA + 16777216);        // 0.26 MB
    u16* fVth    = (u16*)(wsb + oRA + 17825792);          // 8.45 MB
    u16* fKl     = (u16*)(wsb + oRA + 26279936);          // 8.45 MB
    u16* Woh     = (u16*)(wsb + oRA);
    u16* Wol     = (u16*)(wsb + oRA + 2097152);
    u16* ffhh    = (u16*)(wsb + oRA);
    u16* ffhl    = (u16*)(wsb + oRA + 16777216);
    u16* outbh   = (u16*)(wsb + oRA + 33554432);
    u16* outbl   = (u16*)(wsb + oRA + 37748736);
    u16* newQh   = (u16*)(wsb + oRA);
    u16* newQl   = (u16*)(wsb + oRA + 4194304);
    u16* hzh     = (u16*)(wsb + oRA + 8388608);
    u16* hzl     = (u16*)(wsb + oRA + 10485760);
    float* memq  = (float*)(wsb + oRA + 12582912);
    float* partA0 = (float*)(wsb + oRA);
    float* partA1 = (float*)(wsb + oRA + 4194304);
    float* partA2 = (float*)(wsb + oRA + 16777216);
    // region B
    float* Vb    = (float*)(wsb + oRB + 8388608);
    u16* tokh    = (u16*)(wsb + oRB);
    u16* tokl    = (u16*)(wsb + oRB + 8454144);
    u16* oh      = (u16*)(wsb + oRB);
    u16* ol      = (u16*)(wsb + oRB + 4194304);
    u16* y1h     = (u16*)(wsb + oRB + 8388608);
    u16* y1l     = (u16*)(wsb + oRB + 12582912);
    float* partB = (float*)(wsb + oRB);
    // region C
    u16* xh      = (u16*)(wsb + oRC);
    u16* xl      = (u16*)(wsb + oRC + 4194304);
    float* mom   = (float*)(wsb + oRC);
    u16* pW2Th   = (u16*)(wsb + oRC + 5242880);
    u16* pW2Tl   = (u16*)(wsb + oRC + 6291456);
    u16* Wqah    = (u16*)(wsb + oRC);
    u16* Wqal    = (u16*)(wsb + oRC + 6291456);
    // region D
    u16* Qh      = (u16*)(wsb + oRD);
    u16* Ql      = (u16*)(wsb + oRD + 4194304);
    u16* kchh    = (u16*)(wsb + oRD + 8388608);
    u16* kchl    = (u16*)(wsb + oRD + 12582912);
    u16* t1h     = (u16*)(wsb + oRD + 8388608);
    u16* t1l     = (u16*)(wsb + oRD + 10485760);
    u16* fKh     = (u16*)(wsb + oRD);
    u16* ffW1h   = (u16*)(wsb + oRD);
    u16* ffW1l   = (u16*)(wsb + oRD + 8388608);
    u16* ffW2h   = (u16*)(wsb + oRD);
    u16* ffW2l   = (u16*)(wsb + oRD + 8388608);
    // persistent
    u16* Wqkvh   = (u16*)(wsb + oRE);
    u16* Wqkvl   = (u16*)(wsb + oRE + 6291456);
    u16* pW1h    = (u16*)(wsb + oRF);
    u16* pW1l    = (u16*)(wsb + oRF + 1048576);
    u16* pW2h    = (u16*)(wsb + oRF + 2097152);
    u16* pW2l    = (u16*)(wsb + oRF + 3145728);
    float* par   = (float*)(wsb + oRG);
    float* outb  = (float*)(wsb + oRH);
    u16* fQh     = (u16*)(wsb + oRH);
    // fQl slot free (Q hi-only)

    // init memory-MLP params
    hipMemcpyAsync(par + PW1, mW1, 524288 * sizeof(float), hipMemcpyDeviceToDevice, stream);
    hipMemcpyAsync(par + PB1, mb1, 512 * sizeof(float), hipMemcpyDeviceToDevice, stream);
    hipMemcpyAsync(par + PW2, mW2, 524288 * sizeof(float), hipMemcpyDeviceToDevice, stream);
    hipMemcpyAsync(par + PB2, mb2, 1024 * sizeof(float), hipMemcpyDeviceToDevice, stream);

    // qkv = x @ Wqkv^T (fused epilogue; 2-product; column-major XCD chunks)
    cvt_split_k<<<2048, 256, 0, stream>>>(x, xh, xl, 524288);
    cvt_split_k<<<3072, 256, 0, stream>>>(Wqkv, Wqkvh, Wqkvl, 786432);
    gemm_qkv_k<<<dim3(24, 16), 256, 0, stream>>>(xh, xl, Wqkvh, Wqkvl,
        Qh, Ql, kchh, kchl, kcTh, kcTl, Vb, 2048, 3072, 1024);

    // scan prep (xh/xl dead now)
    hipMemsetAsync(mom, 0, PSZ * sizeof(float), stream);
    cvt_split_k<<<512, 256, 0, stream>>>(par + PW1, pW1h, pW1l, 131072);
    cvt_split_k<<<512, 256, 0, stream>>>(par + PW2, pW2h, pW2l, 131072);
    transpose_split_k<<<dim3(16, 32, 1), 256, 0, stream>>>(par + PW2, pW2Th, pW2Tl, 1024, 512);

    // memory scan: z1 -> r -> {gW2 || dh} -> gW1 -> update  (BK=64 dbuf, 2-product)
    const float cs = 2.f / (float)(BATCH * 128 * DIMD);
    for (int c = 0; c < NCH; ++c) {
        const u16* kch = kchh + (size_t)c * 262144;
        const u16* kcl = kchl + (size_t)c * 262144;
        const u16* kth = kcTh + (size_t)c * 262144;
        const u16* ktl = kcTl + (size_t)c * 262144;
        const float* vc = Vb + (size_t)c * 262144;
        gemm_scan_k<1><<<dim3(4, 2), 256, 0, stream>>>(kch, kcl, pW1h, pW1l,
            z1, hh_, hl_, hTh, hTl, nullptr, nullptr, par + PB1, nullptr, 256, 512, 1024, 1.f);
        gemm_scan_k<2><<<dim3(8, 2), 256, 0, stream>>>(hh_, hl_, pW2h, pW2l,
            nullptr, rh_, rl_, rTh, rTl, nullptr, vc, par + PB2, cp2, 256, 1024, 512, cs);
        gemm_scan_pair_k<<<dim3(4, 10), 256, 0, stream>>>(rTh, rTl, hTh, hTl, grd + PW2,
            rh_, rl_, pW2Th, pW2Tl, dhTh, dhTl, z1, cp1, cs);
        gemm_scan_k<3><<<dim3(8, 4), 256, 0, stream>>>(dhTh, dhTl, kth, ktl,
            grd + PW1, nullptr, nullptr, nullptr, nullptr, nullptr, nullptr, nullptr, nullptr,
            512, 1024, 256, 1.f);
        update3_k<<<4102, 256, 0, stream>>>(par, mom, grd, cp1, cp2,
            pW1h, pW1l, pW2h, pW2l, pW2Th, pW2Tl, (int)PSZ);
    }

    // memory readout: t1 (split-K S=4, 2-prod), memtok partial (2-prod) -> tok rows
    gemm_mfma_sk(stream, 1, 0, 1, Qh, Ql, pW1h, pW1l, nullptr, t1h, t1l,
                 2048, 512, 1024, par + PB1, 4, partA2, 2);
    {
        dim3 g(8, 16, 2), b(256);
        gemm_mfma_k<0,0,0,1,2><<<g, b, 0, stream>>>(t1h, t1l, pW2h, pW2l,
            partA0, nullptr, nullptr, 2048, 1024, 512, nullptr, 0);
        reduce_tok_k<<<2048, 256, 0, stream>>>(partA0, par + PB2, tokh, tokl);
    }

    // P + x token rows, weights, fused attention qkv (2-product, dead-Q-tile skip)
    tokens_px_k<<<8320, 256, 0, stream>>>(Pp, x, tokh, tokl);
    cvt_split_k<<<3072, 256, 0, stream>>>(Wqa, Wqah, Wqal, 786432);
    gemm_aqkv_k<<<dim3(24, 33), 256, 0, stream>>>(tokh, tokl, Wqah, Wqal,
        fQh, fKh, fKl, fVth, 4128, 3072, 1024);

    // MFMA flash attention: fixed-shift softmax, P/Q hi-only, MFMA row-sum
    flash_part_k<<<dim3(16, 16, 4), 256, 0, stream>>>(fQh, fKh, fKl, fVth, Of, Lf);
    flash_merge_k<<<dim3(16, 16, 2), 256, 0, stream>>>(Of, Lf, oh, ol);

    // Wo projection + FFN (split-K; 2-product; FF1 column-major chunks)
    cvt_split_k<<<1024, 256, 0, stream>>>(Wo, Woh, Wol, 262144);
    gemm_mfma_sk(stream, 0, 0, 1, oh, ol, Woh, Wol, nullptr, y1h, y1l,
                 2048, 1024, 1024, nullptr, 2, partA1, 2);
    cvt_split_k<<<4096, 256, 0, stream>>>(ffW1, ffW1h, ffW1l, 1048576);
    gemm_mfma(stream, 2, 0, 1, y1h, y1l, ffW1h, ffW1l, nullptr, ffhh, ffhl,
              2048, 4096, 1024, ffb1, 2, 1);
    cvt_split_k<<<4096, 256, 0, stream>>>(ffW2, ffW2h, ffW2l, 1048576);
    gemm_mfma_sk(stream, 0, 1, 1, ffhh, ffhl, ffW2h, ffW2l, outb, outbh, outbl,
                 2048, 1024, 4096, ffb2, 2, partB, 2);

    // gate (newQ/hz 2-product; memq 3-product endpoint anchor)
    gemm_mfma_sk(stream, 0, 0, 1, outbh, outbl, Wqkvh, Wqkvl, nullptr, newQh, newQl,
                 2048, 1024, 1024, nullptr, 2, partB, 2);
    gemm_mfma_sk(stream, 1, 0, 1, newQh, newQl, pW1h, pW1l, nullptr, hzh, hzl,
                 2048, 512, 1024, par + PB1, 4, partB, 2);
    gemm_mfma_sk(stream, 0, 1, 0, hzh, hzl, pW2h, pW2l, memq, nullptr, nullptr,
                 2048, 1024, 512, par + PB2, 2, partB, 3);
    mul_k<<<8192, 256, 0, stream>>>(outb, memq, outp, 2097152);
}